// Round 6
// baseline (449.308 us; speedup 1.0000x reference)
//
#include <hip/hip_runtime.h>
#include <math.h>

// ---------------- constants ----------------
#define BB    8
#define NN    512
#define CIN   64
#define MAXN  16
#define NF    32
#define MID   16
#define BN_   4096        // B*N
#define MSL   65536       // B*N*MAXN
#define MTOT  65568       // MSL + NF
#define RROWS 2098176     // MTOT*NF  (= 8196*256 = 2049*1024)
#define P2STR 40          // LDS row stride in ushorts (80 B, 16B-aligned, conflict-light)

typedef unsigned short ushort_t;
typedef __attribute__((ext_vector_type(8))) short bf16x8;
typedef __attribute__((ext_vector_type(4))) float f32x4;

// ---------------- helpers ----------------
__device__ __forceinline__ float mishf(float x){
  float t  = __expf(x);
  float u  = 1.0f + t;
  float u2 = u * u;
  float r  = x * (u2 - 1.0f) * __builtin_amdgcn_rcpf(u2 + 1.0f);
  return (x > 15.0f) ? x : r;
}

__device__ __forceinline__ ushort_t f2bf(float f){
  unsigned u = __float_as_uint(f);
  unsigned r = (u + 0x7FFFu + ((u >> 16) & 1u)) >> 16;   // RNE
  return (ushort_t)r;
}

// HW packed f32->bf16 convert (gfx950), RNE; bit-identical to f2bf.
__device__ __forceinline__ unsigned cvt_pk_bf16(float lo, float hi){
  unsigned r;
  asm("v_cvt_pk_bf16_f32 %0, %1, %2" : "=v"(r) : "v"(lo), "v"(hi));
  return r;
}

__device__ __forceinline__ unsigned rotl32(unsigned v, unsigned s){
  return (v << s) | (v >> (32u - s));
}

// threefry2x32(key=(0,42), x=(0,0)) -> bits = out0 ^ out1  [verified]
__device__ __forceinline__ float jax_uniform42(){
  unsigned ks[3];
  ks[0] = 0u; ks[1] = 42u; ks[2] = 0x1BD11BDAu ^ 0u ^ 42u;
  const unsigned rot[8] = {13u,15u,26u,6u,17u,29u,16u,24u};
  unsigned x0 = ks[0];
  unsigned x1 = ks[1];
  #pragma unroll
  for (int blk = 0; blk < 5; ++blk){
    #pragma unroll
    for (int r = 0; r < 4; ++r){
      x0 += x1;
      x1 = rotl32(x1, rot[(blk & 1) * 4 + r]);
      x1 ^= x0;
    }
    x0 += ks[(blk + 1) % 3];
    x1 += ks[(blk + 2) % 3] + (unsigned)(blk + 1);
  }
  unsigned w = x0 ^ x1;
  return __uint_as_float((w >> 9) | 0x3f800000u) - 1.0f;
}

// ---------------- k_sq ----------------
__global__ __launch_bounds__(256) void k_sq(const float* __restrict__ x, double* __restrict__ sqd){
  int r = blockIdx.x * 256 + threadIdx.x;
  const float4* p = (const float4*)(x + (size_t)r * 64);
  double a0 = 0.0, a1 = 0.0, a2 = 0.0, a3 = 0.0;
  #pragma unroll
  for (int k = 0; k < 16; k += 4){
    float4 v0 = p[k], v1 = p[k+1], v2 = p[k+2], v3 = p[k+3];
    a0 += (double)v0.x*v0.x + (double)v0.y*v0.y + (double)v0.z*v0.z + (double)v0.w*v0.w;
    a1 += (double)v1.x*v1.x + (double)v1.y*v1.y + (double)v1.z*v1.z + (double)v1.w*v1.w;
    a2 += (double)v2.x*v2.x + (double)v2.y*v2.y + (double)v2.z*v2.z + (double)v2.w*v2.w;
    a3 += (double)v3.x*v3.x + (double)v3.y*v3.y + (double)v3.z*v3.z + (double)v3.w*v3.w;
  }
  sqd[r] = (a0 + a1) + (a2 + a3);
}

// ---------------- kNN top-16 (f64) ----------------
__global__ __launch_bounds__(256) void k_topk(const float* __restrict__ x, const double* __restrict__ sqd,
                                              int* __restrict__ idxp){
  __shared__ float ct[128 * 65];
  __shared__ float xnl[4][64];
  int tid  = threadIdx.x;
  int lane = tid & 63;
  int wid  = tid >> 6;
  int g = blockIdx.x * 4 + wid;
  int b = g >> 9;
  const float* xb = x + (size_t)b * (NN * CIN);
  {
    int w = tid >> 6, c = tid & 63;
    int nq = (blockIdx.x * 4 + w) & 511;
    xnl[w][c] = xb[nq * 64 + c];
  }
  double sqn = sqd[g];

  double dst[8];
  #pragma unroll 1
  for (int tile = 0; tile < 4; ++tile){
    __syncthreads();
    #pragma unroll
    for (int u = 0; u < 8; ++u){
      int idx = u * 256 + tid;
      int row = idx >> 4, q = idx & 15;
      float4 v = *(const float4*)&xb[(size_t)(tile * 128 + row) * 64 + q * 4];
      float* d = &ct[row * 65 + q * 4];
      d[0] = v.x; d[1] = v.y; d[2] = v.z; d[3] = v.w;
    }
    __syncthreads();
    double a[2][4];
    #pragma unroll
    for (int s = 0; s < 2; ++s)
      #pragma unroll
      for (int i = 0; i < 4; ++i) a[s][i] = 0.0;
    #pragma unroll
    for (int k = 0; k < 16; ++k){
      float4 qv = *(const float4*)&xnl[wid][k * 4];
      double q0 = (double)qv.x, q1 = (double)qv.y, q2 = (double)qv.z, q3 = (double)qv.w;
      #pragma unroll
      for (int s = 0; s < 2; ++s){
        const float* rp = &ct[(lane + 64 * s) * 65 + k * 4];
        a[s][0] += q0 * (double)rp[0];
        a[s][1] += q1 * (double)rp[1];
        a[s][2] += q2 * (double)rp[2];
        a[s][3] += q3 * (double)rp[3];
      }
    }
    #pragma unroll
    for (int s = 0; s < 2; ++s){
      int m = tile * 128 + 64 * s + lane;
      dst[tile * 2 + s] = sqn + sqd[(b << 9) + m] - 2.0 * ((a[s][0] + a[s][1]) + (a[s][2] + a[s][3]));
    }
  }

  for (int it = 0; it < 16; ++it){
    double bd = 1.0e300; int bi = 0x7FFFFFFF;
    #pragma unroll
    for (int j = 0; j < 8; ++j){
      int m = ((j >> 1) << 7) + ((j & 1) << 6) + lane;
      if (dst[j] < bd){ bd = dst[j]; bi = m; }
    }
    #pragma unroll
    for (int off = 1; off < 64; off <<= 1){
      double od = __shfl_xor(bd, off);
      int    oi = __shfl_xor(bi, off);
      if (od < bd || (od == bd && oi < bi)){ bd = od; bi = oi; }
    }
    if (lane == 0) idxp[g * 16 + it] = bi;
    if (lane == (bi & 63)){
      int slot = ((bi >> 7) << 1) | ((bi >> 6) & 1);
      #pragma unroll
      for (int j = 0; j < 8; ++j) if (j == slot) dst[j] = 1.0e300;
    }
  }
}

// ---------------- k_prep ----------------
__global__ __launch_bounds__(256) void k_prep(const float* __restrict__ xyz,
                                              const float* __restrict__ fpts,
                                              const int* __restrict__ idxp,
                                              const float* __restrict__ w0, const float* __restrict__ b0,
                                              float* __restrict__ sib, float* __restrict__ fjt){
  __shared__ float w0l[96], b0l[32];
  int tid = threadIdx.x;
  if (tid < 96) w0l[tid] = w0[tid];
  else if (tid < 128) b0l[tid - 96] = b0[tid - 96];
  __syncthreads();
  int i = blockIdx.x * 256 + tid;
  if (i >= MTOT) return;
  float vx, vy, vz;
  if (i < MSL){
    int bn = i >> 4, m = i & 15, b = bn >> 9;
    int i0 = idxp[bn * 16];
    int im = idxp[bn * 16 + m];
    const float* xz = xyz + (size_t)b * (NN * 3);
    vx = xz[im * 3 + 0] - xz[i0 * 3 + 0];
    vy = xz[im * 3 + 1] - xz[i0 * 3 + 1];
    vz = xz[im * 3 + 2] - xz[i0 * 3 + 2];
  } else {
    int j = i - MSL;
    float u   = jax_uniform42();
    float ang = (u * 2.0f) * 3.14159274f;
    float c = cosf(ang), s = sinf(ang);
    float fx = fpts[j * 3 + 0], fy = fpts[j * 3 + 1], fz = fpts[j * 3 + 2];
    vx = fx * c - fz * s;
    vy = fy;
    vz = fx * s + fz * c;
  }
  float si[32];
  #pragma unroll
  for (int c = 0; c < 32; ++c)
    si[c] = vx * w0l[c] + vy * w0l[32 + c] + vz * w0l[64 + c];
  float* dst = sib + (size_t)i * 32;
  #pragma unroll
  for (int cq = 0; cq < 8; ++cq){
    float4 o = make_float4(si[cq*4+0] + b0l[cq*4+0], si[cq*4+1] + b0l[cq*4+1],
                           si[cq*4+2] + b0l[cq*4+2], si[cq*4+3] + b0l[cq*4+3]);
    *(float4*)&dst[cq*4] = o;
  }
  if (i >= MSL){
    int j = i - MSL;
    #pragma unroll
    for (int c = 0; c < 32; ++c) fjt[c * 32 + j] = si[c];
  }
}

// ---------------- m1 pass 1: stats of mish(L0) + optional row-major a0 bf16 store ----------------
// [store path verified in R3 passing run; nullptr path verified R2/R5]
__global__ __launch_bounds__(256) void k_m1_p1(const float* __restrict__ sib, const float* __restrict__ fjt,
                                               float* __restrict__ s0g, float* __restrict__ q0g,
                                               ushort_t* __restrict__ a0g){
  __shared__ float fjlt[32 * 33];
  __shared__ float red[16][32], redq[16][32];
  int tid = threadIdx.x;
  for (int t = tid; t < 1024; t += 256) fjlt[(t & 31) * 33 + (t >> 5)] = fjt[t];
  __syncthreads();
  int c2 = (tid & 15) * 2, s = tid >> 4;
  float as0 = 0.0f, aq0 = 0.0f, as1 = 0.0f, aq1 = 0.0f;
  int base = blockIdx.x * 1024;
  #pragma unroll 4
  for (int t = 0; t < 64; ++t){
    int r = base + t * 16 + s;
    int i = r >> 5, j = r & 31;
    float2 v = *(const float2*)&sib[(size_t)i * 32 + c2];
    float2 f = *(const float2*)&fjlt[j * 33 + c2];
    float m0 = mishf(v.x - f.x);
    float m1 = mishf(v.y - f.y);
    as0 += m0; aq0 += m0 * m0;
    as1 += m1; aq1 += m1 * m1;
    if (a0g) *(unsigned*)&a0g[(size_t)r * 32 + c2] = cvt_pk_bf16(m0, m1);
  }
  red[s][c2] = as0;  red[s][c2 + 1] = as1;
  redq[s][c2] = aq0; redq[s][c2 + 1] = aq1;
  __syncthreads();
  if (tid < 32){
    float ts = 0.0f, tq = 0.0f;
    #pragma unroll
    for (int ss = 0; ss < 16; ++ss){ ts += red[ss][tid]; tq += redq[ss][tid]; }
    int bank = (blockIdx.x & 15) * 32 + tid;
    atomicAdd(&s0g[bank], ts);
    atomicAdd(&q0g[bank], tq);
  }
}

// ---------------- m1 setup: fold BN0 stats into weights ONCE [verified R3/R5] ----------------
__global__ __launch_bounds__(256) void k_m1_setup(const float* __restrict__ w1g, const float* __restrict__ b1g,
                                                  const float* __restrict__ g0, const float* __restrict__ be0,
                                                  const float* __restrict__ s0g, const float* __restrict__ q0g,
                                                  float* __restrict__ biasXg, ushort_t* __restrict__ wtsb){
  __shared__ float A0l[32], C0l[32];
  int tid = threadIdx.x;
  if (tid < 32){
    float s = 0.0f, q = 0.0f;
    #pragma unroll
    for (int b = 0; b < 16; ++b){ s += s0g[b * 32 + tid]; q += q0g[b * 32 + tid]; }
    const float invR = 1.0f / (float)RROWS;
    float mu = s * invR, var = q * invR - mu * mu;
    float A = g0[tid] * rsqrtf(var + 1e-3f);
    A0l[tid] = A; C0l[tid] = be0[tid] - mu * A;
  }
  __syncthreads();
  if (tid < 32){
    float acc = b1g[tid];
    #pragma unroll
    for (int k = 0; k < 32; ++k) acc += C0l[k] * w1g[k * 32 + tid];
    biasXg[tid] = acc;
  }
  for (int t = tid; t < 1024; t += 256){
    int k = t >> 5, c = t & 31;
    wtsb[c * 32 + k] = f2bf(w1g[t] * A0l[k]);
  }
}

// ---------------- m1 pass 2 IN-PLACE: a0 (row-major bf16) -> MFMA -> a1 in-place ----------------
// Fragment loads = R3-verified p2f pattern (direct from global, L3-warm). Epilogue
// transposes through LDS and writes full 64B rows coalesced (fixes R3's 2B-scatter).
// Block b reads and writes only rows [b*256, b*256+256): every wave's a0 reads are
// consumed by its MFMA before the barrier that precedes the write-back -> no hazard.
// Stats scratch lives in the LDS row padding (cols 32..40 of rows 0..15) so total
// LDS is exactly 20480 B -> 8 blocks/CU.
__global__ __launch_bounds__(256, 8) void k_m1_p2i(ushort_t* __restrict__ ab,
                                                   const ushort_t* __restrict__ wtsb,
                                                   const float* __restrict__ biasXg,
                                                   float* __restrict__ s1g, float* __restrict__ q1g){
  __shared__ __align__(16) ushort_t a1s[256 * P2STR];   // 20480 B
  int tid = threadIdx.x;
  #define PADF(i) ((float*)&a1s[((i) >> 2) * P2STR + 32 + (((i) & 3) << 1)])
  if (tid < 32){ *PADF(tid) = 0.0f; *PADF(32 + tid) = 0.0f; }
  int lane = tid & 63, w = tid >> 6;
  int ln15 = lane & 15, quad = lane >> 4;
  bf16x8 bfr0 = *(const bf16x8*)&wtsb[ln15 * 32 + quad * 8];
  bf16x8 bfr1 = *(const bf16x8*)&wtsb[(16 + ln15) * 32 + quad * 8];
  f32x4 zero = {0.0f, 0.0f, 0.0f, 0.0f};
  f32x4 acc[4][2];
  size_t rowt = (size_t)blockIdx.x * 256;
  #pragma unroll
  for (int i2 = 0; i2 < 4; ++i2){
    int row = (w * 4 + i2) * 16 + ln15;
    bf16x8 af = *(const bf16x8*)&ab[(rowt + row) * 32 + quad * 8];
    acc[i2][0] = __builtin_amdgcn_mfma_f32_16x16x32_bf16(af, bfr0, zero, 0, 0, 0);
    acc[i2][1] = __builtin_amdgcn_mfma_f32_16x16x32_bf16(af, bfr1, zero, 0, 0, 0);
  }
  float cs[2] = {0.0f, 0.0f}, cq2[2] = {0.0f, 0.0f};
  #pragma unroll
  for (int nt = 0; nt < 2; ++nt){
    int col = nt * 16 + ln15;
    float bx = biasXg[col];
    #pragma unroll
    for (int i2 = 0; i2 < 4; ++i2){
      f32x4 a = acc[i2][nt];
      int rloc = w * 64 + i2 * 16 + quad * 4;
      float m0 = mishf(a[0] + bx);
      float m1 = mishf(a[1] + bx);
      float m2 = mishf(a[2] + bx);
      float m3 = mishf(a[3] + bx);
      cs[nt]  += m0 + m1 + m2 + m3;
      cq2[nt] += m0*m0 + m1*m1 + m2*m2 + m3*m3;
      unsigned p01 = cvt_pk_bf16(m0, m1);
      unsigned p23 = cvt_pk_bf16(m2, m3);
      a1s[(rloc + 0) * P2STR + col] = (ushort_t)p01;
      a1s[(rloc + 1) * P2STR + col] = (ushort_t)(p01 >> 16);
      a1s[(rloc + 2) * P2STR + col] = (ushort_t)p23;
      a1s[(rloc + 3) * P2STR + col] = (ushort_t)(p23 >> 16);
    }
  }
  __syncthreads();
  // coalesced in-place write-back: thread tid owns global row rowt+tid (64 B)
  {
    const uint4* src = (const uint4*)&a1s[tid * P2STR];
    uint4 v0 = src[0], v1 = src[1], v2 = src[2], v3 = src[3];
    uint4* dst = (uint4*)&ab[(rowt + tid) * 32];
    dst[0] = v0; dst[1] = v1; dst[2] = v2; dst[3] = v3;
  }
  // column stats via LDS pad slots
  #pragma unroll
  for (int nt = 0; nt < 2; ++nt){
    float v = cs[nt], u = cq2[nt];
    v += __shfl_xor(v, 16); u += __shfl_xor(u, 16);
    v += __shfl_xor(v, 32); u += __shfl_xor(u, 32);
    if (lane < 16){
      atomicAdd(PADF(nt * 16 + ln15), v);
      atomicAdd(PADF(32 + nt * 16 + ln15), u);
    }
  }
  __syncthreads();
  if (tid < 32){
    int bank = (blockIdx.x & 15) * 32 + tid;
    atomicAdd(&s1g[bank], *PADF(tid));
    atomicAdd(&q1g[bank], *PADF(32 + tid));
  }
  #undef PADF
}

// ---------------- m1 pass 2 (legacy fallback, full recompute) ----------------
__global__ __launch_bounds__(256, 6) void k_m1_p2(const float* __restrict__ sib, const float* __restrict__ fjt,
                                               const float* __restrict__ w1g, const float* __restrict__ b1g,
                                               const float* __restrict__ g0, const float* __restrict__ be0,
                                               const float* __restrict__ s0g, const float* __restrict__ q0g,
                                               float* __restrict__ s1g, float* __restrict__ q1g,
                                               ushort_t* __restrict__ a1b){
  __shared__ __align__(16) ushort_t a0s[256 * P2STR];
  __shared__ __align__(16) float uni[1024];
  __shared__ float A0l[32], C0l[32], biasX[32], satm[32], qatm[32];
  ushort_t* wts = (ushort_t*)uni;
  int tid = threadIdx.x;
  for (int t = tid; t < 1024; t += 256) uni[t] = fjt[t];
  if (tid < 32){
    float s = 0.0f, q = 0.0f;
    #pragma unroll
    for (int b = 0; b < 16; ++b){ s += s0g[b * 32 + tid]; q += q0g[b * 32 + tid]; }
    const float invR = 1.0f / (float)RROWS;
    float mu = s * invR, var = q * invR - mu * mu;
    float A = g0[tid] * rsqrtf(var + 1e-3f);
    A0l[tid] = A; C0l[tid] = be0[tid] - mu * A;
    satm[tid] = 0.0f; qatm[tid] = 0.0f;
  }
  __syncthreads();
  {
    int r = blockIdx.x * 256 + tid;
    int i = r >> 5, j = r & 31;
    const float* sr = sib + (size_t)i * 32;
    ushort_t* dst = &a0s[tid * P2STR];
    #pragma unroll
    for (int cq = 0; cq < 4; ++cq){
      float4 sa = *(const float4*)&sr[cq * 8];
      float4 sb = *(const float4*)&sr[cq * 8 + 4];
      float m0 = mishf(sa.x - uni[(cq*8+0)*32 + j]);
      float m1 = mishf(sa.y - uni[(cq*8+1)*32 + j]);
      float m2 = mishf(sa.z - uni[(cq*8+2)*32 + j]);
      float m3 = mishf(sa.w - uni[(cq*8+3)*32 + j]);
      float m4 = mishf(sb.x - uni[(cq*8+4)*32 + j]);
      float m5 = mishf(sb.y - uni[(cq*8+5)*32 + j]);
      float m6 = mishf(sb.z - uni[(cq*8+6)*32 + j]);
      float m7 = mishf(sb.w - uni[(cq*8+7)*32 + j]);
      uint4 pk;
      pk.x = cvt_pk_bf16(m0, m1);
      pk.y = cvt_pk_bf16(m2, m3);
      pk.z = cvt_pk_bf16(m4, m5);
      pk.w = cvt_pk_bf16(m6, m7);
      *(uint4*)&dst[cq * 8] = pk;
    }
  }
  if (tid < 32){
    float acc = b1g[tid];
    #pragma unroll
    for (int k = 0; k < 32; ++k) acc += C0l[k] * w1g[k * 32 + tid];
    biasX[tid] = acc;
  }
  __syncthreads();
  for (int t = tid; t < 1024; t += 256){
    int k = t >> 5, c = t & 31;
    wts[c * P2STR + k] = f2bf(w1g[t] * A0l[k]);
  }
  __syncthreads();
  int lane = tid & 63, w = tid >> 6;
  int ln15 = lane & 15, quad = lane >> 4;
  f32x4 zero = {0.0f, 0.0f, 0.0f, 0.0f};
  bf16x8 bfr0 = *(bf16x8*)&wts[(ln15) * P2STR + quad * 8];
  bf16x8 bfr1 = *(bf16x8*)&wts[(16 + ln15) * P2STR + quad * 8];
  f32x4 acc[4][2];
  #pragma unroll
  for (int i2 = 0; i2 < 4; ++i2){
    int row = (w * 4 + i2) * 16 + ln15;
    bf16x8 af = *(bf16x8*)&a0s[row * P2STR + quad * 8];
    acc[i2][0] = __builtin_amdgcn_mfma_f32_16x16x32_bf16(af, bfr0, zero, 0, 0, 0);
    acc[i2][1] = __builtin_amdgcn_mfma_f32_16x16x32_bf16(af, bfr1, zero, 0, 0, 0);
  }
  float cs[2] = {0.0f, 0.0f}, cq2[2] = {0.0f, 0.0f};
  size_t rowbase = (size_t)blockIdx.x * 256 + w * 64 + quad * 4;
  #pragma unroll
  for (int nt = 0; nt < 2; ++nt){
    int col = nt * 16 + ln15;
    float bx = biasX[col];
    size_t colbase = (size_t)col * RROWS;
    #pragma unroll
    for (int i2 = 0; i2 < 4; ++i2){
      f32x4 a = acc[i2][nt];
      float m0 = mishf(a[0] + bx);
      float m1 = mishf(a[1] + bx);
      float m2 = mishf(a[2] + bx);
      float m3 = mishf(a[3] + bx);
      cs[nt]  += m0 + m1 + m2 + m3;
      cq2[nt] += m0*m0 + m1*m1 + m2*m2 + m3*m3;
      if (a1b){
        uint2 pk;
        pk.x = cvt_pk_bf16(m0, m1);
        pk.y = cvt_pk_bf16(m2, m3);
        *(uint2*)&a1b[colbase + rowbase + (size_t)i2 * 16] = pk;
      }
    }
  }
  #pragma unroll
  for (int nt = 0; nt < 2; ++nt){
    float v = cs[nt], u = cq2[nt];
    v += __shfl_xor(v, 16); u += __shfl_xor(u, 16);
    v += __shfl_xor(v, 32); u += __shfl_xor(u, 32);
    if (lane < 16){
      atomicAdd(&satm[nt * 16 + ln15], v);
      atomicAdd(&qatm[nt * 16 + ln15], u);
    }
  }
  __syncthreads();
  if (tid < 32){
    int bank = (blockIdx.x & 15) * 32 + tid;
    atomicAdd(&s1g[bank], satm[tid]);
    atomicAdd(&q1g[bank], qatm[tid]);
  }
}

// ---------------- m1 pass 3 (row-major, verified R3): each lane dots one full 64B a1 row ----------------
__global__ __launch_bounds__(256) void k_m1_p3r(const ushort_t* __restrict__ ab,
                                                const float* __restrict__ w2g, const float* __restrict__ b2g,
                                                const float* __restrict__ g1, const float* __restrict__ be1,
                                                const float* __restrict__ s1g, const float* __restrict__ q1g,
                                                float* __restrict__ act2, float* __restrict__ s2g, float* __restrict__ q2g){
  __shared__ float vvl[32], C1l[32], cb2l[1], r2s[4], r2q[4];
  int tid = threadIdx.x;
  if (tid < 32){
    float s = 0.0f, q = 0.0f;
    #pragma unroll
    for (int b = 0; b < 16; ++b){ s += s1g[b * 32 + tid]; q += q1g[b * 32 + tid]; }
    const float invR = 1.0f / (float)RROWS;
    float mu = s * invR, var = q * invR - mu * mu;
    float A = g1[tid] * rsqrtf(var + 1e-3f);
    C1l[tid] = be1[tid] - mu * A;
    vvl[tid] = A * w2g[tid];
  }
  __syncthreads();
  if (tid == 0){
    float a = b2g[0];
    #pragma unroll
    for (int k = 0; k < 32; ++k) a += C1l[k] * w2g[k];
    cb2l[0] = a;
  }
  __syncthreads();
  float cb2 = cb2l[0];
  size_t base = (size_t)blockIdx.x * 1024 + tid;
  float ss = 0.0f, qq = 0.0f;
  #pragma unroll
  for (int k4 = 0; k4 < 4; ++k4){
    size_t r = base + (size_t)k4 * 256;
    const uint4* p = (const uint4*)&ab[r * 32];
    uint4 ua = p[0], ub = p[1], uc = p[2], ud = p[3];
    unsigned us[16] = {ua.x, ua.y, ua.z, ua.w, ub.x, ub.y, ub.z, ub.w,
                       uc.x, uc.y, uc.z, uc.w, ud.x, ud.y, ud.z, ud.w};
    float p0 = 0.0f, p1 = 0.0f;
    #pragma unroll
    for (int q = 0; q < 16; ++q){
      p0 += __uint_as_float(us[q] << 16) * vvl[2 * q];
      p1 += __uint_as_float(us[q] & 0xFFFF0000u) * vvl[2 * q + 1];
    }
    float a2 = mishf(p0 + p1 + cb2);
    act2[r] = a2;
    ss += a2; qq += a2 * a2;
  }
  #pragma unroll
  for (int off = 1; off < 64; off <<= 1){ ss += __shfl_xor(ss, off); qq += __shfl_xor(qq, off); }
  int lane = tid & 63, wid = tid >> 6;
  if (lane == 0){ r2s[wid] = ss; r2q[wid] = qq; }
  __syncthreads();
  if (tid == 0){
    atomicAdd(&s2g[blockIdx.x & 15], r2s[0] + r2s[1] + r2s[2] + r2s[3]);
    atomicAdd(&q2g[blockIdx.x & 15], r2q[0] + r2q[1] + r2q[2] + r2q[3]);
  }
}

// ---------------- m1 pass 3 (fallback, recompute) ----------------
__global__ __launch_bounds__(256, 3) void k_m1_p3f(const float* __restrict__ sib, const float* __restrict__ fjt,
                                               const float* __restrict__ w1g, const float* __restrict__ b1g,
                                               const float* __restrict__ g0, const float* __restrict__ be0,
                                               const float* __restrict__ g1, const float* __restrict__ be1,
                                               const float* __restrict__ w2g, const float* __restrict__ b2g,
                                               const float* __restrict__ s0g, const float* __restrict__ q0g,
                                               const float* __restrict__ s1g, const float* __restrict__ q1g,
                                               float* __restrict__ act2, float* __restrict__ s2g, float* __restrict__ q2g){
  __shared__ float fjl[1024];
  __shared__ float w1s[1024];
  __shared__ float A0l[32], C0l[32], A1l[32], C1l[32], biasX[32], vvl[32];
  __shared__ float a0t[32 * 256];
  __shared__ float cb2l[1];
  __shared__ float r2s[4], r2q[4];
  int tid = threadIdx.x;
  const float invR = 1.0f / (float)RROWS;
  for (int t = tid; t < 1024; t += 256) fjl[t] = fjt[t];
  if (tid < 32){
    float s = 0.0f, q = 0.0f;
    #pragma unroll
    for (int b = 0; b < 16; ++b){ s += s0g[b * 32 + tid]; q += q0g[b * 32 + tid]; }
    float mu = s * invR, var = q * invR - mu * mu;
    float A = g0[tid] * rsqrtf(var + 1e-3f);
    A0l[tid] = A; C0l[tid] = be0[tid] - mu * A;
  } else if (tid < 64){
    int c = tid - 32;
    float s = 0.0f, q = 0.0f;
    #pragma unroll
    for (int b = 0; b < 16; ++b){ s += s1g[b * 32 + c]; q += q1g[b * 32 + c]; }
    float mu = s * invR, var = q * invR - mu * mu;
    float A = g1[c] * rsqrtf(var + 1e-3f);
    A1l[c] = A; C1l[c] = be1[c] - mu * A;
  }
  __syncthreads();
  for (int t = tid; t < 1024; t += 256) w1s[t] = w1g[t] * A0l[t >> 5];
  if (tid < 32){
    float acc = b1g[tid];
    #pragma unroll
    for (int k = 0; k < 32; ++k) acc += C0l[k] * w1g[k * 32 + tid];
    biasX[tid] = acc;
  } else if (tid < 96 && tid >= 64){
    int c = tid - 64;
    vvl[c] = A1l[c] * w2g[c];
  } else if (tid == 96){
    float acc = b2g[0];
    #pragma unroll
    for (int k = 0; k < 32; ++k) acc += C1l[k] * w2g[k];
    cb2l[0] = acc;
  }
  {
    int r = blockIdx.x * 256 + tid;
    int i = r >> 5, j = r & 31;
    const float* sr = sib + (size_t)i * 32;
    #pragma unroll
    for (int cq = 0; cq < 8; ++cq){
      float4 sv = *(const float4*)&sr[cq * 4];
      a0t[(cq*4+0)*256 + tid] = mishf(sv.x - fjl[(cq*4+0)*32 + j]);
      a0t[(cq*4+1)*256 + tid] = mishf(sv.y - fjl[(cq*4+1)*32 + j]);
      a0t[(cq*4+2)*256 + tid] = mishf(sv.z - fjl[(cq*4+2)*32 + j]);
      a0t[(cq*4+3)*256 + tid] = mishf(sv.w - fjl[(cq*4+3)*32 + j]);
    }
  }
  __syncthreads();
  int cg = tid & 7, rg = tid >> 3;
  float acc[8][4];
  #pragma unroll
  for (int i2 = 0; i2 < 8; ++i2)
    #pragma unroll
    for (int j2 = 0; j2 < 4; ++j2) acc[i2][j2] = 0.0f;
  #pragma unroll 4
  for (int k = 0; k < 32; ++k){
    float4 w  = *(const float4*)&w1s[k * 32 + cg * 4];
    float4 aA = *(const float4*)&a0t[k * 256 + rg * 8];
    float4 aB = *(const float4*)&a0t[k * 256 + rg * 8 + 4];
    float ar[8] = {aA.x, aA.y, aA.z, aA.w, aB.x, aB.y, aB.z, aB.w};
    float wc[4] = {w.x, w.y, w.z, w.w};
    #pragma unroll
    for (int i2 = 0; i2 < 8; ++i2)
      #pragma unroll
      for (int j2 = 0; j2 < 4; ++j2) acc[i2][j2] += ar[i2] * wc[j2];
  }
  float cb2 = cb2l[0];
  float ss = 0.0f, qq = 0.0f;
  #pragma unroll
  for (int rr = 0; rr < 8; ++rr){
    float part = 0.0f;
    #pragma unroll
    for (int cc = 0; cc < 4; ++cc){
      float m = mishf(acc[rr][cc] + biasX[cg * 4 + cc]);
      part += m * vvl[cg * 4 + cc];
    }
    part += __shfl_xor(part, 1);
    part += __shfl_xor(part, 2);
    part += __shfl_xor(part, 4);
    float a2 = mishf(part + cb2);
    if (cg == 0){
      act2[(size_t)blockIdx.x * 256 + rg * 8 + rr] = a2;
      ss += a2; qq += a2 * a2;
    }
  }
  #pragma unroll
  for (int off = 1; off < 64; off <<= 1){ ss += __shfl_xor(ss, off); qq += __shfl_xor(qq, off); }
  int lane = tid & 63, wid = tid >> 6;
  if (lane == 0){ r2s[wid] = ss; r2q[wid] = qq; }
  __syncthreads();
  if (tid == 0){
    atomicAdd(&s2g[blockIdx.x & 15], r2s[0] + r2s[1] + r2s[2] + r2s[3]);
    atomicAdd(&q2g[blockIdx.x & 15], r2q[0] + r2q[1] + r2q[2] + r2q[3]);
  }
}

// ---------------- m2 MLP layer 1 (K-split) ----------------
__global__ __launch_bounds__(512) void k_wmlp1(const float* __restrict__ fpw, const float* __restrict__ W0,
                                               float* __restrict__ wact0){
  int f = blockIdx.x, kc = blockIdx.y, c = threadIdx.x;
  const float* row = fpw + (size_t)f * 4096 + kc * 512;
  const float* wp  = W0 + (size_t)(kc * 512) * 512 + c;
  float acc = 0.0f;
  #pragma unroll 8
  for (int k = 0; k < 512; ++k) acc += row[k] * wp[(size_t)k * 512];
  atomicAdd(&wact0[f * 512 + c], acc);
}

// ---------------- m2 MLP finish ----------------
__global__ __launch_bounds__(512) void k_wmlp2(const float* __restrict__ wact0, const float* __restrict__ b0,
                                               const float* __restrict__ W1,
                                               const float* __restrict__ b1,
                                               const float* __restrict__ g0, const float* __restrict__ be0,
                                               const float* __restrict__ g1, const float* __restrict__ be1,
                                               float* __restrict__ wfin){
  __shared__ float wl[32 * 512];
  __shared__ float o2l[512], A1l[16], C1l[16];
  int t = threadIdx.x;
  {
    float b0t = b0[t];
    float v[32]; float sum = 0.0f, sq = 0.0f;
    #pragma unroll
    for (int r = 0; r < 32; ++r){
      v[r] = mishf(wact0[r * 512 + t] + b0t);
      sum += v[r]; sq += v[r] * v[r];
    }
    float mu  = sum * (1.0f / 32.0f);
    float var = sq * (1.0f / 32.0f) - mu * mu;
    float A = g0[t] * rsqrtf(var + 1e-3f);
    float C = be0[t] - mu * A;
    #pragma unroll
    for (int r = 0; r < 32; ++r) wl[r * 512 + t] = v[r] * A + C;
  }
  __syncthreads();
  {
    int r = t >> 4, c2 = t & 15;
    float pre = b1[c2];
    for (int k = 0; k < 512; ++k) pre += wl[r * 512 + k] * W1[k * 16 + c2];
    o2l[t] = mishf(pre);
  }
  __syncthreads();
  if (t < 16){
    float sum = 0.0f, sq = 0.0f;
    #pragma unroll
    for (int r = 0; r < 32; ++r){ float v = o2l[r * 16 + t]; sum += v; sq += v * v; }
    float mu  = sum * (1.0f / 32.0f);
    float var = sq * (1.0f / 32.0f) - mu * mu;
    float A = g1[t] * rsqrtf(var + 1e-3f);
    A1l[t] = A; C1l[t] = be1[t] - mu * A;
  }
  __syncthreads();
  wfin[t] = o2l[t] * A1l[t & 15] + C1l[t & 15];
}

// ---------------- aggregation + per-point einsum -> fb16[4096,1024] bf16 ----------------
__global__ __launch_bounds__(256) void k_agg(const float* __restrict__ act2, const float* __restrict__ wfin,
                                             const float* __restrict__ x, const int* __restrict__ idxp,
                                             const float* __restrict__ s2, const float* __restrict__ q2,
                                             const float* __restrict__ g2, const float* __restrict__ be2,
                                             ushort_t* __restrict__ fb16){
  __shared__ float hl[512], wfl[512], wm[256], furl[1024], AC[2];
  int t = threadIdx.x;
  int k = blockIdx.x;
  if (t == 0){
    const float invR = 1.0f / (float)RROWS;
    float ssum = 0.0f, qsum = 0.0f;
    #pragma unroll
    for (int b = 0; b < 16; ++b){ ssum += s2[b]; qsum += q2[b]; }
    float mu  = ssum * invR;
    float var = qsum * invR - mu * mu;
    float A = g2[0] * rsqrtf(var + 1e-3f);
    AC[0] = A; AC[1] = be2[0] - mu * A;
  }
  wfl[t] = wfin[t]; wfl[t + 256] = wfin[t + 256];
  __syncthreads();
  float A2 = AC[0], C2 = AC[1];
  hl[t]       = act2[(size_t)k * 512 + t]       * A2 + C2;
  hl[t + 256] = act2[(size_t)k * 512 + 256 + t] * A2 + C2;
  __syncthreads();
  {
    int m = t >> 4, d = t & 15;
    float acc = 0.0f;
    #pragma unroll
    for (int j = 0; j < 32; ++j) acc += hl[m * 32 + j] * wfl[j * 16 + d];
    wm[t] = acc;
  }
  int b = k >> 9;
  const float* xb = x + (size_t)b * (NN * CIN);
  {
    int c = t & 63;
    #pragma unroll
    for (int it = 0; it < 4; ++it){
      int m = it * 4 + (t >> 6);
      int im = idxp[k * 16 + m];
      furl[m * 64 + c] = xb[im * 64 + c];
    }
  }
  __syncthreads();
  {
    int d = t & 15, c0 = t >> 4;
    #pragma unroll
    for (int q = 0; q < 4; ++q){
      int c = c0 + 16 * q;
      float acc = 0.0f;
      #pragma unroll
      for (int m = 0; m < 16; ++m) acc += furl[m * 64 + c] * wm[m * 16 + d];
      fb16[(size_t)k * 1024 + t + 256 * q] = f2bf(acc);
    }
  }
}

// ---------------- w2bf: mrw0 [1024][512] f32 -> Wb [512][1024] bf16 (one-time transpose) ----------------
__global__ __launch_bounds__(256) void k_w2bf(const float* __restrict__ W, ushort_t* __restrict__ Wb){
  int id = blockIdx.x * 256 + threadIdx.x;   // 65536 threads
  int n  = id >> 7;                           // 512
  int k8 = (id & 127) * 8;                    // 1024/8
  float v[8];
  #pragma unroll
  for (int j = 0; j < 8; ++j) v[j] = W[(size_t)(k8 + j) * 512 + n];
  uint4 p;
  p.x = cvt_pk_bf16(v[0], v[1]);
  p.y = cvt_pk_bf16(v[2], v[3]);
  p.z = cvt_pk_bf16(v[4], v[5]);
  p.w = cvt_pk_bf16(v[6], v[7]);
  *(uint4*)&Wb[(size_t)n * 1024 + k8] = p;
}

// ---------------- mr layer 1: barrier-free streaming bf16 MFMA GEMM ----------------
__global__ __launch_bounds__(256, 8) void k_mr1(const ushort_t* __restrict__ F16, const ushort_t* __restrict__ Wb,
                                             const float* __restrict__ bias, float* __restrict__ out,
                                             float* __restrict__ s3, float* __restrict__ q3){
  __shared__ float csum[64], csq[64];
  int tid = threadIdx.x;
  int m0 = blockIdx.y * 64, n0 = blockIdx.x * 64;
  int lane = tid & 63, w = tid >> 6;
  int ln15 = lane & 15, quad = lane >> 4;
  if (tid < 64){ csum[tid] = 0.0f; csq[tid] = 0.0f; }
  __syncthreads();
  f32x4 acc[4];
  #pragma unroll
  for (int n = 0; n < 4; ++n){ acc[n][0] = 0.0f; acc[n][1] = 0.0f; acc[n][2] = 0.0f; acc[n][3] = 0.0f; }
  const ushort_t* Arow = &F16[(size_t)(m0 + w * 16 + ln15) * 1024 + quad * 8];
  const ushort_t* B0 = &Wb[(size_t)(n0 +  0 + ln15) * 1024 + quad * 8];
  const ushort_t* B1 = &Wb[(size_t)(n0 + 16 + ln15) * 1024 + quad * 8];
  const ushort_t* B2 = &Wb[(size_t)(n0 + 32 + ln15) * 1024 + quad * 8];
  const ushort_t* B3 = &Wb[(size_t)(n0 + 48 + ln15) * 1024 + quad * 8];
  #pragma unroll 4
  for (int k0 = 0; k0 < 1024; k0 += 32){
    bf16x8 af = *(const bf16x8*)&Arow[k0];
    bf16x8 b0 = *(const bf16x8*)&B0[k0];
    bf16x8 b1 = *(const bf16x8*)&B1[k0];
    bf16x8 b2 = *(const bf16x8*)&B2[k0];
    bf16x8 b3 = *(const bf16x8*)&B3[k0];
    acc[0] = __builtin_amdgcn_mfma_f32_16x16x32_bf16(af, b0, acc[0], 0, 0, 0);
    acc[1] = __builtin_amdgcn_mfma_f32_16x16x32_bf16(af, b1, acc[1], 0, 0, 0);
    acc[2] = __builtin_amdgcn_mfma_f32_16x16x32_bf16(af, b2, acc[2], 0, 0, 0);
    acc[3] = __builtin_amdgcn_mfma_f32_16x16x32_bf16(af, b3, acc[3], 0, 0, 0);
  }
  // epilogue: bias + mish + store f32 + column stats
  #pragma unroll
  for (int n = 0; n < 4; ++n){
    int col = n0 + n * 16 + ln15;
    float bv = bias[col];
    f32x4 a = acc[n];
    float s = 0.0f, q = 0.0f;
    #pragma unroll
    for (int r = 0; r < 4; ++r){
      float v = mishf(a[r] + bv);
      int row = m0 + w * 16 + quad * 4 + r;
      out[(size_t)row * 512 + col] = v;
      s += v; q += v * v;
    }
    s += __shfl_xor(s, 16); q += __shfl_xor(q, 16);
    s += __shfl_xor(s, 32); q += __shfl_xor(q, 32);
    if (quad == 0){
      atomicAdd(&csum[n * 16 + ln15], s);
      atomicAdd(&csq[n * 16 + ln15], q);
    }
  }
  __syncthreads();
  if (tid < 64){
    atomicAdd(&s3[n0 + tid], csum[tid]);
    atomicAdd(&q3[n0 + tid], csq[tid]);
  }
}

// ---------------- mr layer 2: bn -> f32 tiled GEMM + mish + stats ----------------
__global__ __launch_bounds__(256) void k_mr2(const float* __restrict__ Ain, const float* __restrict__ W,
                                             const float* __restrict__ bias,
                                             const float* __restrict__ s3, const float* __restrict__ q3,
                                             const float* __restrict__ g0, const float* __restrict__ be0,
                                             float* __restrict__ out, float* __restrict__ s4, float* __restrict__ q4){
  __shared__ float As2[16][68];
  __shared__ float Bs2[16][68];
  __shared__ float A3l[512], C3l[512];
  __shared__ float csum[64], csq[64];
  int tid = threadIdx.x;
  for (int kk = tid; kk < 512; kk += 256){
    const float invR = 1.0f / 4096.0f;
    float mu  = s3[kk] * invR;
    float var = q3[kk] * invR - mu * mu;
    float A = g0[kk] * rsqrtf(var + 1e-3f);
    A3l[kk] = A; C3l[kk] = be0[kk] - mu * A;
  }
  if (tid < 64){ csum[tid] = 0.0f; csq[tid] = 0.0f; }
  __syncthreads();
  int m0 = blockIdx.x * 64;
  int tx = tid & 15, ty = tid >> 4;
  float acc[4][4];
  #pragma unroll
  for (int i = 0; i < 4; ++i)
    #pragma unroll
    for (int j = 0; j < 4; ++j) acc[i][j] = 0.0f;
  int lmm = tid >> 2, lkq = (tid & 3) * 4;
  int lkk = tid >> 4, lnq = (tid & 15) * 4;
  float4 av = *(const float4*)&Ain[(size_t)(m0 + lmm) * 512 + lkq];
  float4 bv = *(const float4*)&W[(size_t)lkk * 64 + lnq];
  for (int k0 = 0; k0 < 512; k0 += 16){
    As2[lkq + 0][lmm] = av.x * A3l[k0 + lkq + 0] + C3l[k0 + lkq + 0];
    As2[lkq + 1][lmm] = av.y * A3l[k0 + lkq + 1] + C3l[k0 + lkq + 1];
    As2[lkq + 2][lmm] = av.z * A3l[k0 + lkq + 2] + C3l[k0 + lkq + 2];
    As2[lkq + 3][lmm] = av.w * A3l[k0 + lkq + 3] + C3l[k0 + lkq + 3];
    *(float4*)&Bs2[lkk][lnq] = bv;
    __syncthreads();
    if (k0 + 16 < 512){
      av = *(const float4*)&Ain[(size_t)(m0 + lmm) * 512 + (k0 + 16) + lkq];
      bv = *(const float4*)&W[(size_t)((k0 + 16) + lkk) * 64 + lnq];
    }
    #pragma unroll
    for (int kk = 0; kk < 16; ++kk){
      float4 a4 = *(const float4*)&As2[kk][ty * 4];
      float4 b4 = *(const float4*)&Bs2[kk][tx * 4];
      float a[4] = {a4.x, a4.y, a4.z, a4.w};
      float bb[4] = {b4.x, b4.y, b4.z, b4.w};
      #pragma unroll
      for (int i = 0; i < 4; ++i)
        #pragma unroll
        for (int j = 0; j < 4; ++j) acc[i][j] += a[i] * bb[j];
    }
    __syncthreads();
  }
  float4 bq = *(const float4*)&bias[tx * 4];
  float bvs[4] = {bq.x, bq.y, bq.z, bq.w};
  float cs[4] = {0,0,0,0}, cq[4] = {0,0,0,0};
  #pragma unroll
  for (int i = 0; i < 4; ++i){
    float v[4];
    #pragma unroll
    for (int j = 0; j < 4; ++j){
      v[j] = mishf(acc[i][j] + bvs[j]);
      cs[j] += v[j]; cq[j] += v[j] * v[j];
    }
    float4 o = make_float4(v[0], v[1], v[2], v[3]);
    *(float4*)&out[(size_t)(m0 + ty * 4 + i) * 64 + tx * 4] = o;
  }
  #pragma unroll
  for (int j = 0; j < 4; ++j){
    float v = cs[j], w = cq[j];
    v += __shfl_xor(v, 16); w += __shfl_xor(w, 16);
    v += __shfl_xor(v, 32); w += __shfl_xor(w, 32);
    if ((tid & 63) < 16){
      atomicAdd(&csum[tx * 4 + j], v);
      atomicAdd(&csq[tx * 4 + j], w);
    }
  }
  __syncthreads();
  if (tid < 64){
    atomicAdd(&s4[tid], csum[tid]);
    atomicAdd(&q4[tid], csq[tid]);
  }
}

// ---------------- final BN -> output ----------------
__global__ __launch_bounds__(256) void k_out(const float* __restrict__ pre,
                                             const float* __restrict__ s4, const float* __restrict__ q4,
                                             const float* __restrict__ g1, const float* __restrict__ be1,
                                             float* __restrict__ outp){
  int e = blockIdx.x * 256 + threadIdx.x;
  int c = e & 63;
  const float invR = 1.0f / 4096.0f;
  float mu  = s4[c] * invR;
  float var = q4[c] * invR - mu * mu;
  float A = g1[c] * rsqrtf(var + 1e-3f);
  outp[e] = pre[e] * A + (be1[c] - mu * A);
}

// ---------------- launcher ----------------
extern "C" void kernel_launch(void* const* d_in, const int* in_sizes, int n_in,
                              void* d_out, int out_size, void* d_ws, size_t ws_size,
                              hipStream_t stream){
  (void)in_sizes; (void)n_in; (void)out_size;
  const float* x    = (const float*)d_in[0];
  const float* xyz  = (const float*)d_in[1];
  const float* fpts = (const float*)d_in[2];
  const float* fpw  = (const float*)d_in[3];
  const float* m1w0 = (const float*)d_in[4];
  const float* m1b0 = (const float*)d_in[5];
  const float* m1g0 = (const float*)d_in[6];
  const float* m1be0= (const float*)d_in[7];
  const float* m1w1 = (const float*)d_in[8];
  const float* m1b1 = (const float*)d_in[9];
  const float* m1g1 = (const float*)d_in[10];
  const float* m1be1= (const float*)d_in[11];
  const float* m1w2 = (const float*)d_in[12];
  const float* m1b2 = (const float*)d_in[13];
  const float* m1g2 = (const float*)d_in[14];
  const float* m1be2= (const float*)d_in[15];
  const float* m2w0 = (const float*)d_in[16];
  const float* m2b0 = (const float*)d_in[17];
  const float* m2g0 = (const float*)d_in[18];
  const float* m2be0= (const float*)d_in[19];
  const float* m2w1 = (const float*)d_in[20];
  const float* m2b1 = (const float*)d_in[21];
  const float* m2g1 = (const float*)d_in[22];
  const float* m2be1= (const float*)d_in[23];
  const float* mrw0 = (const float*)d_in[24];
  const float* mrb0 = (const float*)d_in[25];
  const float* mrg0 = (const float*)d_in[26];
  const float* mrbe0= (const float*)d_in[27];
  const float* mrw1 = (const float*)d_in[28];
  const float* mrb1 = (const float*)d_in[29];
  const float* mrg1 = (const float*)d_in[30];
  const float* mrbe1= (const float*)d_in[31];

  float* wsf = (float*)d_ws;
  float* s0 = wsf + 0;     float* q0 = wsf + 512;
  float* s1 = wsf + 1024;  float* q1 = wsf + 1536;
  float* s2 = wsf + 2048;  float* q2 = wsf + 2064;
  float* s3 = wsf + 2080;  float* q3 = wsf + 2592;
  float* s4 = wsf + 3104;  float* q4 = wsf + 3168;
  int*   idxp = (int*)(wsf + 4096);        // 65536 ints -> ends 69632
  double* sqd = (double*)(wsf + 69632);    // 4096 f64 -> ends 77824
  float* biasXg = wsf + 77824;             // 32 floats -> ends 77856
  ushort_t* wtsb = (ushort_t*)(wsf + 77856); // 1024 bf16 = 512 floats -> ends 78368
  float* wact0= wsf + 332032;              // 32*512 pre-activation accumulator
  float* wfin = wsf + 348416;              // 32*16
  float* act2 = wsf + 348928;              // 2098176
  float* fbuf = wsf + 2447104;             // 4096*1024 f32 region (multi-use)
  float* sib  = fbuf;                      // 65568*32 floats [0 .. 2098176)
  float* fjt  = fbuf + 2098176;            // 1024 floats
  ushort_t* fb16 = (ushort_t*)fbuf;        // 4096*1024 bf16 = first 2097152 floats
  ushort_t* wb16 = (ushort_t*)(fbuf + 2099200); // 512*1024 bf16 = 262144 floats (disjoint)
  float* mact = wsf + 6641408;             // 4096*512
  float* mact2= wsf + 8738560;             // 4096*64  (ends 9000704 floats = 36 MB)

  // ab: shared a0/a1 buffer, [RROWS][32] bf16 row-major. p1 writes a0; p2i overwrites
  // with a1 in place (per-block row-disjoint); p3r consumes. Budget == tier-1.
  size_t need1 = 9000704ULL * 4 + (size_t)RROWS * 32 * 2;
  bool fast = (ws_size >= need1);
  ushort_t* ab = fast ? (ushort_t*)(wsf + 9000704) : nullptr;

  hipMemsetAsync(d_ws, 0, 4096 * sizeof(float), stream);
  hipMemsetAsync(wact0, 0, 16384 * sizeof(float), stream);

  k_w2bf<<<256, 256, 0, stream>>>(mrw0, wb16);
  k_sq<<<16, 256, 0, stream>>>(x, sqd);
  k_topk<<<1024, 256, 0, stream>>>(x, sqd, idxp);
  k_prep<<<257, 256, 0, stream>>>(xyz, fpts, idxp, m1w0, m1b0, sib, fjt);
  k_m1_p1<<<2049, 256, 0, stream>>>(sib, fjt, s0, q0, ab);
  if (fast){
    k_m1_setup<<<1, 256, 0, stream>>>(m1w1, m1b1, m1g0, m1be0, s0, q0, biasXg, wtsb);
    k_m1_p2i<<<8196, 256, 0, stream>>>(ab, wtsb, biasXg, s1, q1);
    k_m1_p3r<<<2049, 256, 0, stream>>>(ab, m1w2, m1b2, m1g1, m1be1, s1, q1, act2, s2, q2);
  } else {
    k_m1_p2<<<8196, 256, 0, stream>>>(sib, fjt, m1w1, m1b1, m1g0, m1be0, s0, q0, s1, q1, nullptr);
    k_m1_p3f<<<8196, 256, 0, stream>>>(sib, fjt, m1w1, m1b1, m1g0, m1be0, m1g1, m1be1,
                                       m1w2, m1b2, s0, q0, s1, q1, act2, s2, q2);
  }
  k_wmlp1<<<dim3(32, 8), 512, 0, stream>>>(fpw, m2w0, wact0);
  k_wmlp2<<<1, 512, 0, stream>>>(wact0, m2b0, m2w1, m2b1, m2g0, m2be0, m2g1, m2be1, wfin);
  k_agg<<<4096, 256, 0, stream>>>(act2, wfin, x, idxp, s2, q2, m1g2, m1be2, fb16);
  k_mr1<<<dim3(8, 64), 256, 0, stream>>>(fb16, wb16, mrb0, mact, s3, q3);
  k_mr2<<<64, 256, 0, stream>>>(mact, mrw1, mrb1, s3, q3, mrg0, mrbe0, mact2, s4, q4);
  k_out<<<1024, 256, 0, stream>>>(mact2, s4, q4, mrg1, mrbe1, (float*)d_out);
}

// Round 7
// 424.447 us; speedup vs baseline: 1.0586x; 1.0586x over previous
//
#include <hip/hip_runtime.h>
#include <math.h>

// ---------------- constants ----------------
#define BB    8
#define NN    512
#define CIN   64
#define MAXN  16
#define NF    32
#define MID   16
#define BN_   4096        // B*N
#define MSL   65536       // B*N*MAXN
#define MTOT  65568       // MSL + NF
#define RROWS 2098176     // MTOT*NF  (= 8196*256 = 2049*1024)
#define P2STR 40          // LDS row stride in ushorts (80 B, 16B-aligned, conflict-light)

typedef unsigned short ushort_t;
typedef __attribute__((ext_vector_type(8))) short bf16x8;
typedef __attribute__((ext_vector_type(4))) float f32x4;

// ---------------- helpers ----------------
__device__ __forceinline__ float mishf(float x){
  float t  = __expf(x);
  float u  = 1.0f + t;
  float u2 = u * u;
  float r  = x * (u2 - 1.0f) * __builtin_amdgcn_rcpf(u2 + 1.0f);
  return (x > 15.0f) ? x : r;
}

__device__ __forceinline__ ushort_t f2bf(float f){
  unsigned u = __float_as_uint(f);
  unsigned r = (u + 0x7FFFu + ((u >> 16) & 1u)) >> 16;   // RNE
  return (ushort_t)r;
}

// HW packed f32->bf16 convert (gfx950), RNE; bit-identical to f2bf.
__device__ __forceinline__ unsigned cvt_pk_bf16(float lo, float hi){
  unsigned r;
  asm("v_cvt_pk_bf16_f32 %0, %1, %2" : "=v"(r) : "v"(lo), "v"(hi));
  return r;
}

__device__ __forceinline__ unsigned rotl32(unsigned v, unsigned s){
  return (v << s) | (v >> (32u - s));
}

// threefry2x32(key=(0,42), x=(0,0)) -> bits = out0 ^ out1  [verified]
__device__ __forceinline__ float jax_uniform42(){
  unsigned ks[3];
  ks[0] = 0u; ks[1] = 42u; ks[2] = 0x1BD11BDAu ^ 0u ^ 42u;
  const unsigned rot[8] = {13u,15u,26u,6u,17u,29u,16u,24u};
  unsigned x0 = ks[0];
  unsigned x1 = ks[1];
  #pragma unroll
  for (int blk = 0; blk < 5; ++blk){
    #pragma unroll
    for (int r = 0; r < 4; ++r){
      x0 += x1;
      x1 = rotl32(x1, rot[(blk & 1) * 4 + r]);
      x1 ^= x0;
    }
    x0 += ks[(blk + 1) % 3];
    x1 += ks[(blk + 2) % 3] + (unsigned)(blk + 1);
  }
  unsigned w = x0 ^ x1;
  return __uint_as_float((w >> 9) | 0x3f800000u) - 1.0f;
}

// ---------------- k_sq ----------------
__global__ __launch_bounds__(256) void k_sq(const float* __restrict__ x, double* __restrict__ sqd){
  int r = blockIdx.x * 256 + threadIdx.x;
  const float4* p = (const float4*)(x + (size_t)r * 64);
  double a0 = 0.0, a1 = 0.0, a2 = 0.0, a3 = 0.0;
  #pragma unroll
  for (int k = 0; k < 16; k += 4){
    float4 v0 = p[k], v1 = p[k+1], v2 = p[k+2], v3 = p[k+3];
    a0 += (double)v0.x*v0.x + (double)v0.y*v0.y + (double)v0.z*v0.z + (double)v0.w*v0.w;
    a1 += (double)v1.x*v1.x + (double)v1.y*v1.y + (double)v1.z*v1.z + (double)v1.w*v1.w;
    a2 += (double)v2.x*v2.x + (double)v2.y*v2.y + (double)v2.z*v2.z + (double)v2.w*v2.w;
    a3 += (double)v3.x*v3.x + (double)v3.y*v3.y + (double)v3.z*v3.z + (double)v3.w*v3.w;
  }
  sqd[r] = (a0 + a1) + (a2 + a3);
}

// ---------------- kNN top-16 (f64) ----------------
__global__ __launch_bounds__(256) void k_topk(const float* __restrict__ x, const double* __restrict__ sqd,
                                              int* __restrict__ idxp){
  __shared__ float ct[128 * 65];
  __shared__ float xnl[4][64];
  int tid  = threadIdx.x;
  int lane = tid & 63;
  int wid  = tid >> 6;
  int g = blockIdx.x * 4 + wid;
  int b = g >> 9;
  const float* xb = x + (size_t)b * (NN * CIN);
  {
    int w = tid >> 6, c = tid & 63;
    int nq = (blockIdx.x * 4 + w) & 511;
    xnl[w][c] = xb[nq * 64 + c];
  }
  double sqn = sqd[g];

  double dst[8];
  #pragma unroll 1
  for (int tile = 0; tile < 4; ++tile){
    __syncthreads();
    #pragma unroll
    for (int u = 0; u < 8; ++u){
      int idx = u * 256 + tid;
      int row = idx >> 4, q = idx & 15;
      float4 v = *(const float4*)&xb[(size_t)(tile * 128 + row) * 64 + q * 4];
      float* d = &ct[row * 65 + q * 4];
      d[0] = v.x; d[1] = v.y; d[2] = v.z; d[3] = v.w;
    }
    __syncthreads();
    double a[2][4];
    #pragma unroll
    for (int s = 0; s < 2; ++s)
      #pragma unroll
      for (int i = 0; i < 4; ++i) a[s][i] = 0.0;
    #pragma unroll
    for (int k = 0; k < 16; ++k){
      float4 qv = *(const float4*)&xnl[wid][k * 4];
      double q0 = (double)qv.x, q1 = (double)qv.y, q2 = (double)qv.z, q3 = (double)qv.w;
      #pragma unroll
      for (int s = 0; s < 2; ++s){
        const float* rp = &ct[(lane + 64 * s) * 65 + k * 4];
        a[s][0] += q0 * (double)rp[0];
        a[s][1] += q1 * (double)rp[1];
        a[s][2] += q2 * (double)rp[2];
        a[s][3] += q3 * (double)rp[3];
      }
    }
    #pragma unroll
    for (int s = 0; s < 2; ++s){
      int m = tile * 128 + 64 * s + lane;
      dst[tile * 2 + s] = sqn + sqd[(b << 9) + m] - 2.0 * ((a[s][0] + a[s][1]) + (a[s][2] + a[s][3]));
    }
  }

  for (int it = 0; it < 16; ++it){
    double bd = 1.0e300; int bi = 0x7FFFFFFF;
    #pragma unroll
    for (int j = 0; j < 8; ++j){
      int m = ((j >> 1) << 7) + ((j & 1) << 6) + lane;
      if (dst[j] < bd){ bd = dst[j]; bi = m; }
    }
    #pragma unroll
    for (int off = 1; off < 64; off <<= 1){
      double od = __shfl_xor(bd, off);
      int    oi = __shfl_xor(bi, off);
      if (od < bd || (od == bd && oi < bi)){ bd = od; bi = oi; }
    }
    if (lane == 0) idxp[g * 16 + it] = bi;
    if (lane == (bi & 63)){
      int slot = ((bi >> 7) << 1) | ((bi >> 6) & 1);
      #pragma unroll
      for (int j = 0; j < 8; ++j) if (j == slot) dst[j] = 1.0e300;
    }
  }
}

// ---------------- k_prep ----------------
__global__ __launch_bounds__(256) void k_prep(const float* __restrict__ xyz,
                                              const float* __restrict__ fpts,
                                              const int* __restrict__ idxp,
                                              const float* __restrict__ w0, const float* __restrict__ b0,
                                              float* __restrict__ sib, float* __restrict__ fjt){
  __shared__ float w0l[96], b0l[32];
  int tid = threadIdx.x;
  if (tid < 96) w0l[tid] = w0[tid];
  else if (tid < 128) b0l[tid - 96] = b0[tid - 96];
  __syncthreads();
  int i = blockIdx.x * 256 + tid;
  if (i >= MTOT) return;
  float vx, vy, vz;
  if (i < MSL){
    int bn = i >> 4, m = i & 15, b = bn >> 9;
    int i0 = idxp[bn * 16];
    int im = idxp[bn * 16 + m];
    const float* xz = xyz + (size_t)b * (NN * 3);
    vx = xz[im * 3 + 0] - xz[i0 * 3 + 0];
    vy = xz[im * 3 + 1] - xz[i0 * 3 + 1];
    vz = xz[im * 3 + 2] - xz[i0 * 3 + 2];
  } else {
    int j = i - MSL;
    float u   = jax_uniform42();
    float ang = (u * 2.0f) * 3.14159274f;
    float c = cosf(ang), s = sinf(ang);
    float fx = fpts[j * 3 + 0], fy = fpts[j * 3 + 1], fz = fpts[j * 3 + 2];
    vx = fx * c - fz * s;
    vy = fy;
    vz = fx * s + fz * c;
  }
  float si[32];
  #pragma unroll
  for (int c = 0; c < 32; ++c)
    si[c] = vx * w0l[c] + vy * w0l[32 + c] + vz * w0l[64 + c];
  float* dst = sib + (size_t)i * 32;
  #pragma unroll
  for (int cq = 0; cq < 8; ++cq){
    float4 o = make_float4(si[cq*4+0] + b0l[cq*4+0], si[cq*4+1] + b0l[cq*4+1],
                           si[cq*4+2] + b0l[cq*4+2], si[cq*4+3] + b0l[cq*4+3]);
    *(float4*)&dst[cq*4] = o;
  }
  if (i >= MSL){
    int j = i - MSL;
    #pragma unroll
    for (int c = 0; c < 32; ++c) fjt[c * 32 + j] = si[c];
  }
}

// ---------------- m1 pass 1: stats of mish(L0), float4-vectorized ----------------
// thread = (c4 = (tid&7)*4, s = tid>>3); 32 iters x 32 rows; float4 global + float4 LDS.
// Reduce via padded red[32][33] (conflict-free: bank (ss+tid)%32 per fixed ss).
__global__ __launch_bounds__(256) void k_m1_p1(const float* __restrict__ sib, const float* __restrict__ fjt,
                                               float* __restrict__ s0g, float* __restrict__ q0g){
  __shared__ float fjlt[32 * 36];            // [j][c], stride 36
  __shared__ float red[32][33], redq[32][33];
  int tid = threadIdx.x;
  for (int t = tid; t < 1024; t += 256) fjlt[(t & 31) * 36 + (t >> 5)] = fjt[t];
  __syncthreads();
  int c4 = (tid & 7) * 4, s = tid >> 3;      // s in [0,32)
  float as[4], aq[4];
  #pragma unroll
  for (int k = 0; k < 4; ++k){ as[k] = 0.0f; aq[k] = 0.0f; }
  int base = blockIdx.x * 1024;
  #pragma unroll 4
  for (int t = 0; t < 32; ++t){
    int r = base + t * 32 + s;
    int i = r >> 5, j = r & 31;
    float4 v = *(const float4*)&sib[(size_t)i * 32 + c4];
    float4 f = *(const float4*)&fjlt[j * 36 + c4];
    float m0 = mishf(v.x - f.x);
    float m1 = mishf(v.y - f.y);
    float m2 = mishf(v.z - f.z);
    float m3 = mishf(v.w - f.w);
    as[0] += m0; aq[0] += m0 * m0;
    as[1] += m1; aq[1] += m1 * m1;
    as[2] += m2; aq[2] += m2 * m2;
    as[3] += m3; aq[3] += m3 * m3;
  }
  #pragma unroll
  for (int k = 0; k < 4; ++k){ red[s][c4 + k] = as[k]; redq[s][c4 + k] = aq[k]; }
  __syncthreads();
  if (tid < 32){
    float ts = 0.0f, tq = 0.0f;
    #pragma unroll
    for (int ss = 0; ss < 32; ++ss){ ts += red[ss][tid]; tq += redq[ss][tid]; }
    int bank = (blockIdx.x & 15) * 32 + tid;
    atomicAdd(&s0g[bank], ts);
    atomicAdd(&q0g[bank], tq);
  }
}

// ---------------- m1 setup: fold BN0 stats into weights ONCE [verified R3/R5] ----------------
__global__ __launch_bounds__(256) void k_m1_setup(const float* __restrict__ w1g, const float* __restrict__ b1g,
                                                  const float* __restrict__ g0, const float* __restrict__ be0,
                                                  const float* __restrict__ s0g, const float* __restrict__ q0g,
                                                  float* __restrict__ biasXg, ushort_t* __restrict__ wtsb){
  __shared__ float A0l[32], C0l[32];
  int tid = threadIdx.x;
  if (tid < 32){
    float s = 0.0f, q = 0.0f;
    #pragma unroll
    for (int b = 0; b < 16; ++b){ s += s0g[b * 32 + tid]; q += q0g[b * 32 + tid]; }
    const float invR = 1.0f / (float)RROWS;
    float mu = s * invR, var = q * invR - mu * mu;
    float A = g0[tid] * rsqrtf(var + 1e-3f);
    A0l[tid] = A; C0l[tid] = be0[tid] - mu * A;
  }
  __syncthreads();
  if (tid < 32){
    float acc = b1g[tid];
    #pragma unroll
    for (int k = 0; k < 32; ++k) acc += C0l[k] * w1g[k * 32 + tid];
    biasXg[tid] = acc;
  }
  for (int t = tid; t < 1024; t += 256){
    int k = t >> 5, c = t & 31;
    wtsb[c * 32 + k] = f2bf(w1g[t] * A0l[k]);
  }
}

// ---------------- m1 pass 2 HOISTED [verified R5] + PADF stats [verified R6] ----------------
// LDS = exactly 20480 B (stats live in a0s row padding) -> 8 blocks/CU (160 KB).
__global__ __launch_bounds__(256, 8) void k_m1_p2h(const float* __restrict__ sib, const float* __restrict__ fjt,
                                                   const ushort_t* __restrict__ wtsb,
                                                   const float* __restrict__ biasXg,
                                                   float* __restrict__ s1g, float* __restrict__ q1g,
                                                   ushort_t* __restrict__ a1b){
  __shared__ __align__(16) ushort_t a0s[256 * P2STR];    // 20480 B total (incl. pad stats)
  int tid = threadIdx.x;
  #define PADF(i) ((float*)&a0s[((i) >> 2) * P2STR + 32 + (((i) & 3) << 1)])
  if (tid < 32){ *PADF(tid) = 0.0f; *PADF(32 + tid) = 0.0f; }
  {
    int r = blockIdx.x * 256 + tid;
    int i = r >> 5, j = r & 31;
    const float* sr = sib + (size_t)i * 32;
    ushort_t* dst = &a0s[tid * P2STR];
    #pragma unroll
    for (int cq = 0; cq < 4; ++cq){
      float4 sa = *(const float4*)&sr[cq * 8];
      float4 sb = *(const float4*)&sr[cq * 8 + 4];
      float m0 = mishf(sa.x - fjt[(cq*8+0)*32 + j]);
      float m1 = mishf(sa.y - fjt[(cq*8+1)*32 + j]);
      float m2 = mishf(sa.z - fjt[(cq*8+2)*32 + j]);
      float m3 = mishf(sa.w - fjt[(cq*8+3)*32 + j]);
      float m4 = mishf(sb.x - fjt[(cq*8+4)*32 + j]);
      float m5 = mishf(sb.y - fjt[(cq*8+5)*32 + j]);
      float m6 = mishf(sb.z - fjt[(cq*8+6)*32 + j]);
      float m7 = mishf(sb.w - fjt[(cq*8+7)*32 + j]);
      uint4 pk;
      pk.x = cvt_pk_bf16(m0, m1);
      pk.y = cvt_pk_bf16(m2, m3);
      pk.z = cvt_pk_bf16(m4, m5);
      pk.w = cvt_pk_bf16(m6, m7);
      *(uint4*)&dst[cq * 8] = pk;
    }
  }
  __syncthreads();
  int lane = tid & 63, w = tid >> 6;
  int ln15 = lane & 15, quad = lane >> 4;
  f32x4 zero = {0.0f, 0.0f, 0.0f, 0.0f};
  bf16x8 bfr0 = *(const bf16x8*)&wtsb[ln15 * 32 + quad * 8];
  bf16x8 bfr1 = *(const bf16x8*)&wtsb[(16 + ln15) * 32 + quad * 8];
  f32x4 acc[4][2];
  #pragma unroll
  for (int i2 = 0; i2 < 4; ++i2){
    int row = (w * 4 + i2) * 16 + ln15;
    bf16x8 af = *(bf16x8*)&a0s[row * P2STR + quad * 8];
    acc[i2][0] = __builtin_amdgcn_mfma_f32_16x16x32_bf16(af, bfr0, zero, 0, 0, 0);
    acc[i2][1] = __builtin_amdgcn_mfma_f32_16x16x32_bf16(af, bfr1, zero, 0, 0, 0);
  }
  float cs[2] = {0.0f, 0.0f}, cq2[2] = {0.0f, 0.0f};
  size_t rowbase = (size_t)blockIdx.x * 256 + w * 64 + quad * 4;
  #pragma unroll
  for (int nt = 0; nt < 2; ++nt){
    int col = nt * 16 + ln15;
    float bx = biasXg[col];
    size_t colbase = (size_t)col * RROWS;
    #pragma unroll
    for (int i2 = 0; i2 < 4; ++i2){
      f32x4 a = acc[i2][nt];
      float m0 = mishf(a[0] + bx);
      float m1 = mishf(a[1] + bx);
      float m2 = mishf(a[2] + bx);
      float m3 = mishf(a[3] + bx);
      cs[nt]  += m0 + m1 + m2 + m3;
      cq2[nt] += m0*m0 + m1*m1 + m2*m2 + m3*m3;
      uint2 pk;
      pk.x = cvt_pk_bf16(m0, m1);
      pk.y = cvt_pk_bf16(m2, m3);
      *(uint2*)&a1b[colbase + rowbase + (size_t)i2 * 16] = pk;
    }
  }
  #pragma unroll
  for (int nt = 0; nt < 2; ++nt){
    float v = cs[nt], u = cq2[nt];
    v += __shfl_xor(v, 16); u += __shfl_xor(u, 16);
    v += __shfl_xor(v, 32); u += __shfl_xor(u, 32);
    if (lane < 16){
      atomicAdd(PADF(nt * 16 + ln15), v);
      atomicAdd(PADF(32 + nt * 16 + ln15), u);
    }
  }
  __syncthreads();
  if (tid < 32){
    int bank = (blockIdx.x & 15) * 32 + tid;
    atomicAdd(&s1g[bank], *PADF(tid));
    atomicAdd(&q1g[bank], *PADF(32 + tid));
  }
  #undef PADF
}

// ---------------- m1 pass 2 (legacy fallback, full recompute) ----------------
__global__ __launch_bounds__(256, 6) void k_m1_p2(const float* __restrict__ sib, const float* __restrict__ fjt,
                                               const float* __restrict__ w1g, const float* __restrict__ b1g,
                                               const float* __restrict__ g0, const float* __restrict__ be0,
                                               const float* __restrict__ s0g, const float* __restrict__ q0g,
                                               float* __restrict__ s1g, float* __restrict__ q1g,
                                               ushort_t* __restrict__ a1b){
  __shared__ __align__(16) ushort_t a0s[256 * P2STR];
  __shared__ __align__(16) float uni[1024];
  __shared__ float A0l[32], C0l[32], biasX[32], satm[32], qatm[32];
  ushort_t* wts = (ushort_t*)uni;
  int tid = threadIdx.x;
  for (int t = tid; t < 1024; t += 256) uni[t] = fjt[t];
  if (tid < 32){
    float s = 0.0f, q = 0.0f;
    #pragma unroll
    for (int b = 0; b < 16; ++b){ s += s0g[b * 32 + tid]; q += q0g[b * 32 + tid]; }
    const float invR = 1.0f / (float)RROWS;
    float mu = s * invR, var = q * invR - mu * mu;
    float A = g0[tid] * rsqrtf(var + 1e-3f);
    A0l[tid] = A; C0l[tid] = be0[tid] - mu * A;
    satm[tid] = 0.0f; qatm[tid] = 0.0f;
  }
  __syncthreads();
  {
    int r = blockIdx.x * 256 + tid;
    int i = r >> 5, j = r & 31;
    const float* sr = sib + (size_t)i * 32;
    ushort_t* dst = &a0s[tid * P2STR];
    #pragma unroll
    for (int cq = 0; cq < 4; ++cq){
      float4 sa = *(const float4*)&sr[cq * 8];
      float4 sb = *(const float4*)&sr[cq * 8 + 4];
      float m0 = mishf(sa.x - uni[(cq*8+0)*32 + j]);
      float m1 = mishf(sa.y - uni[(cq*8+1)*32 + j]);
      float m2 = mishf(sa.z - uni[(cq*8+2)*32 + j]);
      float m3 = mishf(sa.w - uni[(cq*8+3)*32 + j]);
      float m4 = mishf(sb.x - uni[(cq*8+4)*32 + j]);
      float m5 = mishf(sb.y - uni[(cq*8+5)*32 + j]);
      float m6 = mishf(sb.z - uni[(cq*8+6)*32 + j]);
      float m7 = mishf(sb.w - uni[(cq*8+7)*32 + j]);
      uint4 pk;
      pk.x = cvt_pk_bf16(m0, m1);
      pk.y = cvt_pk_bf16(m2, m3);
      pk.z = cvt_pk_bf16(m4, m5);
      pk.w = cvt_pk_bf16(m6, m7);
      *(uint4*)&dst[cq * 8] = pk;
    }
  }
  if (tid < 32){
    float acc = b1g[tid];
    #pragma unroll
    for (int k = 0; k < 32; ++k) acc += C0l[k] * w1g[k * 32 + tid];
    biasX[tid] = acc;
  }
  __syncthreads();
  for (int t = tid; t < 1024; t += 256){
    int k = t >> 5, c = t & 31;
    wts[c * P2STR + k] = f2bf(w1g[t] * A0l[k]);
  }
  __syncthreads();
  int lane = tid & 63, w = tid >> 6;
  int ln15 = lane & 15, quad = lane >> 4;
  f32x4 zero = {0.0f, 0.0f, 0.0f, 0.0f};
  bf16x8 bfr0 = *(bf16x8*)&wts[(ln15) * P2STR + quad * 8];
  bf16x8 bfr1 = *(bf16x8*)&wts[(16 + ln15) * P2STR + quad * 8];
  f32x4 acc[4][2];
  #pragma unroll
  for (int i2 = 0; i2 < 4; ++i2){
    int row = (w * 4 + i2) * 16 + ln15;
    bf16x8 af = *(bf16x8*)&a0s[row * P2STR + quad * 8];
    acc[i2][0] = __builtin_amdgcn_mfma_f32_16x16x32_bf16(af, bfr0, zero, 0, 0, 0);
    acc[i2][1] = __builtin_amdgcn_mfma_f32_16x16x32_bf16(af, bfr1, zero, 0, 0, 0);
  }
  float cs[2] = {0.0f, 0.0f}, cq2[2] = {0.0f, 0.0f};
  size_t rowbase = (size_t)blockIdx.x * 256 + w * 64 + quad * 4;
  #pragma unroll
  for (int nt = 0; nt < 2; ++nt){
    int col = nt * 16 + ln15;
    float bx = biasX[col];
    size_t colbase = (size_t)col * RROWS;
    #pragma unroll
    for (int i2 = 0; i2 < 4; ++i2){
      f32x4 a = acc[i2][nt];
      float m0 = mishf(a[0] + bx);
      float m1 = mishf(a[1] + bx);
      float m2 = mishf(a[2] + bx);
      float m3 = mishf(a[3] + bx);
      cs[nt]  += m0 + m1 + m2 + m3;
      cq2[nt] += m0*m0 + m1*m1 + m2*m2 + m3*m3;
      if (a1b){
        uint2 pk;
        pk.x = cvt_pk_bf16(m0, m1);
        pk.y = cvt_pk_bf16(m2, m3);
        *(uint2*)&a1b[colbase + rowbase + (size_t)i2 * 16] = pk;
      }
    }
  }
  #pragma unroll
  for (int nt = 0; nt < 2; ++nt){
    float v = cs[nt], u = cq2[nt];
    v += __shfl_xor(v, 16); u += __shfl_xor(u, 16);
    v += __shfl_xor(v, 32); u += __shfl_xor(u, 32);
    if (lane < 16){
      atomicAdd(&satm[nt * 16 + ln15], v);
      atomicAdd(&qatm[nt * 16 + ln15], u);
    }
  }
  __syncthreads();
  if (tid < 32){
    int bank = (blockIdx.x & 15) * 32 + tid;
    atomicAdd(&s1g[bank], satm[tid]);
    atomicAdd(&q1g[bank], qatm[tid]);
  }
}

// ---------------- m1 pass 3 (streaming): col-major a1b, 8 rows/thread [verified R2/R5] ----------------
__global__ __launch_bounds__(256) void k_m1_p3s(const ushort_t* __restrict__ a1b,
                                                const float* __restrict__ w2g, const float* __restrict__ b2g,
                                                const float* __restrict__ g1, const float* __restrict__ be1,
                                                const float* __restrict__ s1g, const float* __restrict__ q1g,
                                                float* __restrict__ act2, float* __restrict__ s2g, float* __restrict__ q2g){
  __shared__ float vvl[32], C1l[32], cb2l[1], r2s[4], r2q[4];
  int tid = threadIdx.x;
  if (tid < 32){
    float s = 0.0f, q = 0.0f;
    #pragma unroll
    for (int b = 0; b < 16; ++b){ s += s1g[b * 32 + tid]; q += q1g[b * 32 + tid]; }
    const float invR = 1.0f / (float)RROWS;
    float mu = s * invR, var = q * invR - mu * mu;
    float A = g1[tid] * rsqrtf(var + 1e-3f);
    C1l[tid] = be1[tid] - mu * A;
    vvl[tid] = A * w2g[tid];
  }
  __syncthreads();
  if (tid == 0){
    float a = b2g[0];
    #pragma unroll
    for (int k = 0; k < 32; ++k) a += C1l[k] * w2g[k];
    cb2l[0] = a;
  }
  __syncthreads();
  size_t r0 = (size_t)blockIdx.x * 2048 + (size_t)tid * 8;
  float ss = 0.0f, qq = 0.0f;
  if (r0 < (size_t)RROWS){
    float pre[8];
    #pragma unroll
    for (int j = 0; j < 8; ++j) pre[j] = 0.0f;
    #pragma unroll 8
    for (int c = 0; c < 32; ++c){
      uint4 u = *(const uint4*)&a1b[(size_t)c * RROWS + r0];
      float vv = vvl[c];
      pre[0] += __uint_as_float(u.x << 16) * vv;
      pre[1] += __uint_as_float(u.x & 0xFFFF0000u) * vv;
      pre[2] += __uint_as_float(u.y << 16) * vv;
      pre[3] += __uint_as_float(u.y & 0xFFFF0000u) * vv;
      pre[4] += __uint_as_float(u.z << 16) * vv;
      pre[5] += __uint_as_float(u.z & 0xFFFF0000u) * vv;
      pre[6] += __uint_as_float(u.w << 16) * vv;
      pre[7] += __uint_as_float(u.w & 0xFFFF0000u) * vv;
    }
    float cb2 = cb2l[0];
    float a2[8];
    #pragma unroll
    for (int j = 0; j < 8; ++j){
      a2[j] = mishf(pre[j] + cb2);
      ss += a2[j]; qq += a2[j] * a2[j];
    }
    *(float4*)&act2[r0]     = make_float4(a2[0], a2[1], a2[2], a2[3]);
    *(float4*)&act2[r0 + 4] = make_float4(a2[4], a2[5], a2[6], a2[7]);
  }
  #pragma unroll
  for (int off = 1; off < 64; off <<= 1){ ss += __shfl_xor(ss, off); qq += __shfl_xor(qq, off); }
  int lane = tid & 63, wid = tid >> 6;
  if (lane == 0){ r2s[wid] = ss; r2q[wid] = qq; }
  __syncthreads();
  if (tid == 0){
    atomicAdd(&s2g[blockIdx.x & 15], r2s[0] + r2s[1] + r2s[2] + r2s[3]);
    atomicAdd(&q2g[blockIdx.x & 15], r2q[0] + r2q[1] + r2q[2] + r2q[3]);
  }
}

// ---------------- m1 pass 3 (fallback, recompute) ----------------
__global__ __launch_bounds__(256, 3) void k_m1_p3f(const float* __restrict__ sib, const float* __restrict__ fjt,
                                               const float* __restrict__ w1g, const float* __restrict__ b1g,
                                               const float* __restrict__ g0, const float* __restrict__ be0,
                                               const float* __restrict__ g1, const float* __restrict__ be1,
                                               const float* __restrict__ w2g, const float* __restrict__ b2g,
                                               const float* __restrict__ s0g, const float* __restrict__ q0g,
                                               const float* __restrict__ s1g, const float* __restrict__ q1g,
                                               float* __restrict__ act2, float* __restrict__ s2g, float* __restrict__ q2g){
  __shared__ float fjl[1024];
  __shared__ float w1s[1024];
  __shared__ float A0l[32], C0l[32], A1l[32], C1l[32], biasX[32], vvl[32];
  __shared__ float a0t[32 * 256];
  __shared__ float cb2l[1];
  __shared__ float r2s[4], r2q[4];
  int tid = threadIdx.x;
  const float invR = 1.0f / (float)RROWS;
  for (int t = tid; t < 1024; t += 256) fjl[t] = fjt[t];
  if (tid < 32){
    float s = 0.0f, q = 0.0f;
    #pragma unroll
    for (int b = 0; b < 16; ++b){ s += s0g[b * 32 + tid]; q += q0g[b * 32 + tid]; }
    float mu = s * invR, var = q * invR - mu * mu;
    float A = g0[tid] * rsqrtf(var + 1e-3f);
    A0l[tid] = A; C0l[tid] = be0[tid] - mu * A;
  } else if (tid < 64){
    int c = tid - 32;
    float s = 0.0f, q = 0.0f;
    #pragma unroll
    for (int b = 0; b < 16; ++b){ s += s1g[b * 32 + c]; q += q1g[b * 32 + c]; }
    float mu = s * invR, var = q * invR - mu * mu;
    float A = g1[c] * rsqrtf(var + 1e-3f);
    A1l[c] = A; C1l[c] = be1[c] - mu * A;
  }
  __syncthreads();
  for (int t = tid; t < 1024; t += 256) w1s[t] = w1g[t] * A0l[t >> 5];
  if (tid < 32){
    float acc = b1g[tid];
    #pragma unroll
    for (int k = 0; k < 32; ++k) acc += C0l[k] * w1g[k * 32 + tid];
    biasX[tid] = acc;
  } else if (tid < 96 && tid >= 64){
    int c = tid - 64;
    vvl[c] = A1l[c] * w2g[c];
  } else if (tid == 96){
    float acc = b2g[0];
    #pragma unroll
    for (int k = 0; k < 32; ++k) acc += C1l[k] * w2g[k];
    cb2l[0] = acc;
  }
  {
    int r = blockIdx.x * 256 + tid;
    int i = r >> 5, j = r & 31;
    const float* sr = sib + (size_t)i * 32;
    #pragma unroll
    for (int cq = 0; cq < 8; ++cq){
      float4 sv = *(const float4*)&sr[cq * 4];
      a0t[(cq*4+0)*256 + tid] = mishf(sv.x - fjl[(cq*4+0)*32 + j]);
      a0t[(cq*4+1)*256 + tid] = mishf(sv.y - fjl[(cq*4+1)*32 + j]);
      a0t[(cq*4+2)*256 + tid] = mishf(sv.z - fjl[(cq*4+2)*32 + j]);
      a0t[(cq*4+3)*256 + tid] = mishf(sv.w - fjl[(cq*4+3)*32 + j]);
    }
  }
  __syncthreads();
  int cg = tid & 7, rg = tid >> 3;
  float acc[8][4];
  #pragma unroll
  for (int i2 = 0; i2 < 8; ++i2)
    #pragma unroll
    for (int j2 = 0; j2 < 4; ++j2) acc[i2][j2] = 0.0f;
  #pragma unroll 4
  for (int k = 0; k < 32; ++k){
    float4 w  = *(const float4*)&w1s[k * 32 + cg * 4];
    float4 aA = *(const float4*)&a0t[k * 256 + rg * 8];
    float4 aB = *(const float4*)&a0t[k * 256 + rg * 8 + 4];
    float ar[8] = {aA.x, aA.y, aA.z, aA.w, aB.x, aB.y, aB.z, aB.w};
    float wc[4] = {w.x, w.y, w.z, w.w};
    #pragma unroll
    for (int i2 = 0; i2 < 8; ++i2)
      #pragma unroll
      for (int j2 = 0; j2 < 4; ++j2) acc[i2][j2] += ar[i2] * wc[j2];
  }
  float cb2 = cb2l[0];
  float ss = 0.0f, qq = 0.0f;
  #pragma unroll
  for (int rr = 0; rr < 8; ++rr){
    float part = 0.0f;
    #pragma unroll
    for (int cc = 0; cc < 4; ++cc){
      float m = mishf(acc[rr][cc] + biasX[cg * 4 + cc]);
      part += m * vvl[cg * 4 + cc];
    }
    part += __shfl_xor(part, 1);
    part += __shfl_xor(part, 2);
    part += __shfl_xor(part, 4);
    float a2 = mishf(part + cb2);
    if (cg == 0){
      act2[(size_t)blockIdx.x * 256 + rg * 8 + rr] = a2;
      ss += a2; qq += a2 * a2;
    }
  }
  #pragma unroll
  for (int off = 1; off < 64; off <<= 1){ ss += __shfl_xor(ss, off); qq += __shfl_xor(qq, off); }
  int lane = tid & 63, wid = tid >> 6;
  if (lane == 0){ r2s[wid] = ss; r2q[wid] = qq; }
  __syncthreads();
  if (tid == 0){
    atomicAdd(&s2g[blockIdx.x & 15], r2s[0] + r2s[1] + r2s[2] + r2s[3]);
    atomicAdd(&q2g[blockIdx.x & 15], r2q[0] + r2q[1] + r2q[2] + r2q[3]);
  }
}

// ---------------- m2 MLP layer 1 (K-split) ----------------
__global__ __launch_bounds__(512) void k_wmlp1(const float* __restrict__ fpw, const float* __restrict__ W0,
                                               float* __restrict__ wact0){
  int f = blockIdx.x, kc = blockIdx.y, c = threadIdx.x;
  const float* row = fpw + (size_t)f * 4096 + kc * 512;
  const float* wp  = W0 + (size_t)(kc * 512) * 512 + c;
  float acc = 0.0f;
  #pragma unroll 8
  for (int k = 0; k < 512; ++k) acc += row[k] * wp[(size_t)k * 512];
  atomicAdd(&wact0[f * 512 + c], acc);
}

// ---------------- m2 MLP finish ----------------
__global__ __launch_bounds__(512) void k_wmlp2(const float* __restrict__ wact0, const float* __restrict__ b0,
                                               const float* __restrict__ W1,
                                               const float* __restrict__ b1,
                                               const float* __restrict__ g0, const float* __restrict__ be0,
                                               const float* __restrict__ g1, const float* __restrict__ be1,
                                               float* __restrict__ wfin){
  __shared__ float wl[32 * 512];
  __shared__ float o2l[512], A1l[16], C1l[16];
  int t = threadIdx.x;
  {
    float b0t = b0[t];
    float v[32]; float sum = 0.0f, sq = 0.0f;
    #pragma unroll
    for (int r = 0; r < 32; ++r){
      v[r] = mishf(wact0[r * 512 + t] + b0t);
      sum += v[r]; sq += v[r] * v[r];
    }
    float mu  = sum * (1.0f / 32.0f);
    float var = sq * (1.0f / 32.0f) - mu * mu;
    float A = g0[t] * rsqrtf(var + 1e-3f);
    float C = be0[t] - mu * A;
    #pragma unroll
    for (int r = 0; r < 32; ++r) wl[r * 512 + t] = v[r] * A + C;
  }
  __syncthreads();
  {
    int r = t >> 4, c2 = t & 15;
    float pre = b1[c2];
    for (int k = 0; k < 512; ++k) pre += wl[r * 512 + k] * W1[k * 16 + c2];
    o2l[t] = mishf(pre);
  }
  __syncthreads();
  if (t < 16){
    float sum = 0.0f, sq = 0.0f;
    #pragma unroll
    for (int r = 0; r < 32; ++r){ float v = o2l[r * 16 + t]; sum += v; sq += v * v; }
    float mu  = sum * (1.0f / 32.0f);
    float var = sq * (1.0f / 32.0f) - mu * mu;
    float A = g1[t] * rsqrtf(var + 1e-3f);
    A1l[t] = A; C1l[t] = be1[t] - mu * A;
  }
  __syncthreads();
  wfin[t] = o2l[t] * A1l[t & 15] + C1l[t & 15];
}

// ---------------- aggregation + per-point einsum -> fb16[4096,1024] bf16 ----------------
__global__ __launch_bounds__(256) void k_agg(const float* __restrict__ act2, const float* __restrict__ wfin,
                                             const float* __restrict__ x, const int* __restrict__ idxp,
                                             const float* __restrict__ s2, const float* __restrict__ q2,
                                             const float* __restrict__ g2, const float* __restrict__ be2,
                                             ushort_t* __restrict__ fb16){
  __shared__ float hl[512], wfl[512], wm[256], furl[1024], AC[2];
  int t = threadIdx.x;
  int k = blockIdx.x;
  if (t == 0){
    const float invR = 1.0f / (float)RROWS;
    float ssum = 0.0f, qsum = 0.0f;
    #pragma unroll
    for (int b = 0; b < 16; ++b){ ssum += s2[b]; qsum += q2[b]; }
    float mu  = ssum * invR;
    float var = qsum * invR - mu * mu;
    float A = g2[0] * rsqrtf(var + 1e-3f);
    AC[0] = A; AC[1] = be2[0] - mu * A;
  }
  wfl[t] = wfin[t]; wfl[t + 256] = wfin[t + 256];
  __syncthreads();
  float A2 = AC[0], C2 = AC[1];
  hl[t]       = act2[(size_t)k * 512 + t]       * A2 + C2;
  hl[t + 256] = act2[(size_t)k * 512 + 256 + t] * A2 + C2;
  __syncthreads();
  {
    int m = t >> 4, d = t & 15;
    float acc = 0.0f;
    #pragma unroll
    for (int j = 0; j < 32; ++j) acc += hl[m * 32 + j] * wfl[j * 16 + d];
    wm[t] = acc;
  }
  int b = k >> 9;
  const float* xb = x + (size_t)b * (NN * CIN);
  {
    int c = t & 63;
    #pragma unroll
    for (int it = 0; it < 4; ++it){
      int m = it * 4 + (t >> 6);
      int im = idxp[k * 16 + m];
      furl[m * 64 + c] = xb[im * 64 + c];
    }
  }
  __syncthreads();
  {
    int d = t & 15, c0 = t >> 4;
    #pragma unroll
    for (int q = 0; q < 4; ++q){
      int c = c0 + 16 * q;
      float acc = 0.0f;
      #pragma unroll
      for (int m = 0; m < 16; ++m) acc += furl[m * 64 + c] * wm[m * 16 + d];
      fb16[(size_t)k * 1024 + t + 256 * q] = f2bf(acc);
    }
  }
}

// ---------------- w2bf: mrw0 [1024][512] f32 -> Wb [512][1024] bf16 (one-time transpose) ----------------
__global__ __launch_bounds__(256) void k_w2bf(const float* __restrict__ W, ushort_t* __restrict__ Wb){
  int id = blockIdx.x * 256 + threadIdx.x;   // 65536 threads
  int n  = id >> 7;                           // 512
  int k8 = (id & 127) * 8;                    // 1024/8
  float v[8];
  #pragma unroll
  for (int j = 0; j < 8; ++j) v[j] = W[(size_t)(k8 + j) * 512 + n];
  uint4 p;
  p.x = cvt_pk_bf16(v[0], v[1]);
  p.y = cvt_pk_bf16(v[2], v[3]);
  p.z = cvt_pk_bf16(v[4], v[5]);
  p.w = cvt_pk_bf16(v[6], v[7]);
  *(uint4*)&Wb[(size_t)n * 1024 + k8] = p;
}

// ---------------- mr layer 1: barrier-free streaming bf16 MFMA GEMM ----------------
__global__ __launch_bounds__(256, 8) void k_mr1(const ushort_t* __restrict__ F16, const ushort_t* __restrict__ Wb,
                                             const float* __restrict__ bias, float* __restrict__ out,
                                             float* __restrict__ s3, float* __restrict__ q3){
  __shared__ float csum[64], csq[64];
  int tid = threadIdx.x;
  int m0 = blockIdx.y * 64, n0 = blockIdx.x * 64;
  int lane = tid & 63, w = tid >> 6;
  int ln15 = lane & 15, quad = lane >> 4;
  if (tid < 64){ csum[tid] = 0.0f; csq[tid] = 0.0f; }
  __syncthreads();
  f32x4 acc[4];
  #pragma unroll
  for (int n = 0; n < 4; ++n){ acc[n][0] = 0.0f; acc[n][1] = 0.0f; acc[n][2] = 0.0f; acc[n][3] = 0.0f; }
  const ushort_t* Arow = &F16[(size_t)(m0 + w * 16 + ln15) * 1024 + quad * 8];
  const ushort_t* B0 = &Wb[(size_t)(n0 +  0 + ln15) * 1024 + quad * 8];
  const ushort_t* B1 = &Wb[(size_t)(n0 + 16 + ln15) * 1024 + quad * 8];
  const ushort_t* B2 = &Wb[(size_t)(n0 + 32 + ln15) * 1024 + quad * 8];
  const ushort_t* B3 = &Wb[(size_t)(n0 + 48 + ln15) * 1024 + quad * 8];
  #pragma unroll 4
  for (int k0 = 0; k0 < 1024; k0 += 32){
    bf16x8 af = *(const bf16x8*)&Arow[k0];
    bf16x8 b0 = *(const bf16x8*)&B0[k0];
    bf16x8 b1 = *(const bf16x8*)&B1[k0];
    bf16x8 b2 = *(const bf16x8*)&B2[k0];
    bf16x8 b3 = *(const bf16x8*)&B3[k0];
    acc[0] = __builtin_amdgcn_mfma_f32_16x16x32_bf16(af, b0, acc[0], 0, 0, 0);
    acc[1] = __builtin_amdgcn_mfma_f32_16x16x32_bf16(af, b1, acc[1], 0, 0, 0);
    acc[2] = __builtin_amdgcn_mfma_f32_16x16x32_bf16(af, b2, acc[2], 0, 0, 0);
    acc[3] = __builtin_amdgcn_mfma_f32_16x16x32_bf16(af, b3, acc[3], 0, 0, 0);
  }
  // epilogue: bias + mish + store f32 + column stats
  #pragma unroll
  for (int n = 0; n < 4; ++n){
    int col = n0 + n * 16 + ln15;
    float bv = bias[col];
    f32x4 a = acc[n];
    float s = 0.0f, q = 0.0f;
    #pragma unroll
    for (int r = 0; r < 4; ++r){
      float v = mishf(a[r] + bv);
      int row = m0 + w * 16 + quad * 4 + r;
      out[(size_t)row * 512 + col] = v;
      s += v; q += v * v;
    }
    s += __shfl_xor(s, 16); q += __shfl_xor(q, 16);
    s += __shfl_xor(s, 32); q += __shfl_xor(q, 32);
    if (quad == 0){
      atomicAdd(&csum[n * 16 + ln15], s);
      atomicAdd(&csq[n * 16 + ln15], q);
    }
  }
  __syncthreads();
  if (tid < 64){
    atomicAdd(&s3[n0 + tid], csum[tid]);
    atomicAdd(&q3[n0 + tid], csq[tid]);
  }
}

// ---------------- mr layer 2: bn -> f32 tiled GEMM + mish + stats ----------------
__global__ __launch_bounds__(256) void k_mr2(const float* __restrict__ Ain, const float* __restrict__ W,
                                             const float* __restrict__ bias,
                                             const float* __restrict__ s3, const float* __restrict__ q3,
                                             const float* __restrict__ g0, const float* __restrict__ be0,
                                             float* __restrict__ out, float* __restrict__ s4, float* __restrict__ q4){
  __shared__ float As2[16][68];
  __shared__ float Bs2[16][68];
  __shared__ float A3l[512], C3l[512];
  __shared__ float csum[64], csq[64];
  int tid = threadIdx.x;
  for (int kk = tid; kk < 512; kk += 256){
    const float invR = 1.0f / 4096.0f;
    float mu  = s3[kk] * invR;
    float var = q3[kk] * invR - mu * mu;
    float A = g0[kk] * rsqrtf(var + 1e-3f);
    A3l[kk] = A; C3l[kk] = be0[kk] - mu * A;
  }
  if (tid < 64){ csum[tid] = 0.0f; csq[tid] = 0.0f; }
  __syncthreads();
  int m0 = blockIdx.x * 64;
  int tx = tid & 15, ty = tid >> 4;
  float acc[4][4];
  #pragma unroll
  for (int i = 0; i < 4; ++i)
    #pragma unroll
    for (int j = 0; j < 4; ++j) acc[i][j] = 0.0f;
  int lmm = tid >> 2, lkq = (tid & 3) * 4;
  int lkk = tid >> 4, lnq = (tid & 15) * 4;
  float4 av = *(const float4*)&Ain[(size_t)(m0 + lmm) * 512 + lkq];
  float4 bv = *(const float4*)&W[(size_t)lkk * 64 + lnq];
  for (int k0 = 0; k0 < 512; k0 += 16){
    As2[lkq + 0][lmm] = av.x * A3l[k0 + lkq + 0] + C3l[k0 + lkq + 0];
    As2[lkq + 1][lmm] = av.y * A3l[k0 + lkq + 1] + C3l[k0 + lkq + 1];
    As2[lkq + 2][lmm] = av.z * A3l[k0 + lkq + 2] + C3l[k0 + lkq + 2];
    As2[lkq + 3][lmm] = av.w * A3l[k0 + lkq + 3] + C3l[k0 + lkq + 3];
    *(float4*)&Bs2[lkk][lnq] = bv;
    __syncthreads();
    if (k0 + 16 < 512){
      av = *(const float4*)&Ain[(size_t)(m0 + lmm) * 512 + (k0 + 16) + lkq];
      bv = *(const float4*)&W[(size_t)((k0 + 16) + lkk) * 64 + lnq];
    }
    #pragma unroll
    for (int kk = 0; kk < 16; ++kk){
      float4 a4 = *(const float4*)&As2[kk][ty * 4];
      float4 b4 = *(const float4*)&Bs2[kk][tx * 4];
      float a[4] = {a4.x, a4.y, a4.z, a4.w};
      float bb[4] = {b4.x, b4.y, b4.z, b4.w};
      #pragma unroll
      for (int i = 0; i < 4; ++i)
        #pragma unroll
        for (int j = 0; j < 4; ++j) acc[i][j] += a[i] * bb[j];
    }
    __syncthreads();
  }
  float4 bq = *(const float4*)&bias[tx * 4];
  float bvs[4] = {bq.x, bq.y, bq.z, bq.w};
  float cs[4] = {0,0,0,0}, cq[4] = {0,0,0,0};
  #pragma unroll
  for (int i = 0; i < 4; ++i){
    float v[4];
    #pragma unroll
    for (int j = 0; j < 4; ++j){
      v[j] = mishf(acc[i][j] + bvs[j]);
      cs[j] += v[j]; cq[j] += v[j] * v[j];
    }
    float4 o = make_float4(v[0], v[1], v[2], v[3]);
    *(float4*)&out[(size_t)(m0 + ty * 4 + i) * 64 + tx * 4] = o;
  }
  #pragma unroll
  for (int j = 0; j < 4; ++j){
    float v = cs[j], w = cq[j];
    v += __shfl_xor(v, 16); w += __shfl_xor(w, 16);
    v += __shfl_xor(v, 32); w += __shfl_xor(w, 32);
    if ((tid & 63) < 16){
      atomicAdd(&csum[tx * 4 + j], v);
      atomicAdd(&csq[tx * 4 + j], w);
    }
  }
  __syncthreads();
  if (tid < 64){
    atomicAdd(&s4[tid], csum[tid]);
    atomicAdd(&q4[tid], csq[tid]);
  }
}

// ---------------- final BN -> output ----------------
__global__ __launch_bounds__(256) void k_out(const float* __restrict__ pre,
                                             const float* __restrict__ s4, const float* __restrict__ q4,
                                             const float* __restrict__ g1, const float* __restrict__ be1,
                                             float* __restrict__ outp){
  int e = blockIdx.x * 256 + threadIdx.x;
  int c = e & 63;
  const float invR = 1.0f / 4096.0f;
  float mu  = s4[c] * invR;
  float var = q4[c] * invR - mu * mu;
  float A = g1[c] * rsqrtf(var + 1e-3f);
  outp[e] = pre[e] * A + (be1[c] - mu * A);
}

// ---------------- launcher ----------------
extern "C" void kernel_launch(void* const* d_in, const int* in_sizes, int n_in,
                              void* d_out, int out_size, void* d_ws, size_t ws_size,
                              hipStream_t stream){
  (void)in_sizes; (void)n_in; (void)out_size;
  const float* x    = (const float*)d_in[0];
  const float* xyz  = (const float*)d_in[1];
  const float* fpts = (const float*)d_in[2];
  const float* fpw  = (const float*)d_in[3];
  const float* m1w0 = (const float*)d_in[4];
  const float* m1b0 = (const float*)d_in[5];
  const float* m1g0 = (const float*)d_in[6];
  const float* m1be0= (const float*)d_in[7];
  const float* m1w1 = (const float*)d_in[8];
  const float* m1b1 = (const float*)d_in[9];
  const float* m1g1 = (const float*)d_in[10];
  const float* m1be1= (const float*)d_in[11];
  const float* m1w2 = (const float*)d_in[12];
  const float* m1b2 = (const float*)d_in[13];
  const float* m1g2 = (const float*)d_in[14];
  const float* m1be2= (const float*)d_in[15];
  const float* m2w0 = (const float*)d_in[16];
  const float* m2b0 = (const float*)d_in[17];
  const float* m2g0 = (const float*)d_in[18];
  const float* m2be0= (const float*)d_in[19];
  const float* m2w1 = (const float*)d_in[20];
  const float* m2b1 = (const float*)d_in[21];
  const float* m2g1 = (const float*)d_in[22];
  const float* m2be1= (const float*)d_in[23];
  const float* mrw0 = (const float*)d_in[24];
  const float* mrb0 = (const float*)d_in[25];
  const float* mrg0 = (const float*)d_in[26];
  const float* mrbe0= (const float*)d_in[27];
  const float* mrw1 = (const float*)d_in[28];
  const float* mrb1 = (const float*)d_in[29];
  const float* mrg1 = (const float*)d_in[30];
  const float* mrbe1= (const float*)d_in[31];

  float* wsf = (float*)d_ws;
  float* s0 = wsf + 0;     float* q0 = wsf + 512;
  float* s1 = wsf + 1024;  float* q1 = wsf + 1536;
  float* s2 = wsf + 2048;  float* q2 = wsf + 2064;
  float* s3 = wsf + 2080;  float* q3 = wsf + 2592;
  float* s4 = wsf + 3104;  float* q4 = wsf + 3168;
  int*   idxp = (int*)(wsf + 4096);        // 65536 ints -> ends 69632
  double* sqd = (double*)(wsf + 69632);    // 4096 f64 -> ends 77824
  float* biasXg = wsf + 77824;             // 32 floats -> ends 77856
  ushort_t* wtsb = (ushort_t*)(wsf + 77856); // 1024 bf16 = 512 floats -> ends 78368
  float* wact0= wsf + 332032;              // 32*512 pre-activation accumulator
  float* wfin = wsf + 348416;              // 32*16
  float* act2 = wsf + 348928;              // 2098176
  float* fbuf = wsf + 2447104;             // 4096*1024 f32 region (multi-use)
  float* sib  = fbuf;                      // 65568*32 floats [0 .. 2098176)
  float* fjt  = fbuf + 2098176;            // 1024 floats
  ushort_t* fb16 = (ushort_t*)fbuf;        // 4096*1024 bf16 = first 2097152 floats
  ushort_t* wb16 = (ushort_t*)(fbuf + 2099200); // 512*1024 bf16 = 262144 floats (disjoint)
  float* mact = wsf + 6641408;             // 4096*512
  float* mact2= wsf + 8738560;             // 4096*64  (ends 9000704 floats = 36 MB)

  // a1b: col-major [32][RROWS] bf16 (written by p2h, read by p3s)
  size_t need1 = 9000704ULL * 4 + (size_t)RROWS * 32 * 2;
  bool fast = (ws_size >= need1);
  ushort_t* a1b = fast ? (ushort_t*)(wsf + 9000704) : nullptr;

  hipMemsetAsync(d_ws, 0, 4096 * sizeof(float), stream);
  hipMemsetAsync(wact0, 0, 16384 * sizeof(float), stream);

  k_w2bf<<<256, 256, 0, stream>>>(mrw0, wb16);
  k_sq<<<16, 256, 0, stream>>>(x, sqd);
  k_topk<<<1024, 256, 0, stream>>>(x, sqd, idxp);
  k_prep<<<257, 256, 0, stream>>>(xyz, fpts, idxp, m1w0, m1b0, sib, fjt);
  k_m1_p1<<<2049, 256, 0, stream>>>(sib, fjt, s0, q0);
  if (fast){
    k_m1_setup<<<1, 256, 0, stream>>>(m1w1, m1b1, m1g0, m1be0, s0, q0, biasXg, wtsb);
    k_m1_p2h<<<8196, 256, 0, stream>>>(sib, fjt, wtsb, biasXg, s1, q1, a1b);
    k_m1_p3s<<<1025, 256, 0, stream>>>(a1b, m1w2, m1b2, m1g1, m1be1, s1, q1, act2, s2, q2);
  } else {
    k_m1_p2<<<8196, 256, 0, stream>>>(sib, fjt, m1w1, m1b1, m1g0, m1be0, s0, q0, s1, q1, nullptr);
    k_m1_p3f<<<8196, 256, 0, stream>>>(sib, fjt, m1w1, m1b1, m1g0, m1be0, m1g1, m1be1,
                                       m1w2, m1b2, s0, q0, s1, q1, act2, s2, q2);
  }
  k_wmlp1<<<dim3(32, 8), 512, 0, stream>>>(fpw, m2w0, wact0);
  k_wmlp2<<<1, 512, 0, stream>>>(wact0, m2b0, m2w1, m2b1, m2g0, m2be0, m2g1, m2be1, wfin);
  k_agg<<<4096, 256, 0, stream>>>(act2, wfin, x, idxp, s2, q2, m1g2, m1be2, fb16);
  k_mr1<<<dim3(8, 64), 256, 0, stream>>>(fb16, wb16, mrb0, mact, s3, q3);
  k_mr2<<<64, 256, 0, stream>>>(mact, mrw1, mrb1, s3, q3, mrg0, mrbe0, mact2, s4, q4);
  k_out<<<1024, 256, 0, stream>>>(mact2, s4, q4, mrg1, mrbe1, (float*)d_out);
}